// Round 4
// baseline (1596.107 us; speedup 1.0000x reference)
//
#include <hip/hip_runtime.h>
#include <hip/hip_bf16.h>

// Problem constants (from reference)
#define NN 50000
#define EE 800000
#define GG 128
#define LL 4
#define TT 4
#define FF 20
#define DD 80
#define SCAN_B ((NN + 1023) / 1024)   // 49
static constexpr float AVG_LOG = 2.8332133440562162f; // ln(17)

typedef __fp16 half2v __attribute__((ext_vector_type(2)));

__device__ __forceinline__ float bf2f(unsigned short u) {
  return __uint_as_float((unsigned)u << 16);
}
__device__ __forceinline__ unsigned short f2bf(float f) {
  __hip_bfloat16 b = __float2bfloat16(f); // RNE
  return *(unsigned short*)&b;
}
__device__ __forceinline__ half2v pkrtz(float a, float b) {
#if __has_builtin(__builtin_amdgcn_cvt_pkrtz)
  return __builtin_amdgcn_cvt_pkrtz(a, b);
#else
  half2v h; h.x = (__fp16)a; h.y = (__fp16)b; return h;
#endif
}
__device__ __forceinline__ float fdot2(half2v a, half2v b, float c) {
#if __has_builtin(__builtin_amdgcn_fdot2)
  return __builtin_amdgcn_fdot2(a, b, c, false);
#else
  return fmaf((float)a.x, (float)b.x, fmaf((float)a.y, (float)b.y, c));
#endif
}
__device__ __forceinline__ half2v u2h2(unsigned int u) {
  return __builtin_bit_cast(half2v, u);
}
__device__ __forceinline__ unsigned int h22u(half2v h) {
  return __builtin_bit_cast(unsigned int, h);
}
__device__ __forceinline__ unsigned int packh2_rne(float a, float b) {
  half2v h; h.x = (__fp16)a; h.y = (__fp16)b; // RNE casts for weights
  return h22u(h);
}
__device__ __forceinline__ unsigned int pack_bf16(float a, float b) {
  return (unsigned int)f2bf(a) | ((unsigned int)f2bf(b) << 16);
}

// ---------------- h init: h[n,d] = sum_i atom_emb[i, x[n,i], d] ----------------
__global__ __launch_bounds__(256) void k_h(const int* __restrict__ x,
                                           const float* __restrict__ atom_emb,
                                           float* __restrict__ h) {
  int idx = blockIdx.x * 256 + threadIdx.x;
  if (idx >= NN * DD) return;
  int n = idx / DD, d = idx - n * DD;
  const int* xr = x + n * 9;
  float acc = 0.f;
#pragma unroll
  for (int i = 0; i < 9; ++i) {
    int v = xr[i];
    acc += atom_emb[(i * 16 + v) * DD + d];
  }
  h[idx] = acc;
}

// ---------------- degree count ----------------
__global__ __launch_bounds__(256) void k_deg(const int* __restrict__ ei, int* __restrict__ cnt) {
  int e = blockIdx.x * 256 + threadIdx.x;
  if (e >= EE) return;
  atomicAdd(&cnt[ei[EE + e]], 1); // dst = edge_index[1][e]
}

// ---------------- hierarchical exclusive scan ----------------
__global__ __launch_bounds__(1024) void k_scan_sum(const int* __restrict__ cnt, int* __restrict__ bsum) {
  __shared__ int red[1024];
  int tid = threadIdx.x;
  int i = blockIdx.x * 1024 + tid;
  red[tid] = (i < NN) ? cnt[i] : 0;
  __syncthreads();
  for (int off = 512; off > 0; off >>= 1) {
    if (tid < off) red[tid] += red[tid + off];
    __syncthreads();
  }
  if (tid == 0) bsum[blockIdx.x] = red[0];
}

__global__ void k_scan_top(const int* __restrict__ bsum, int* __restrict__ boff,
                           int* __restrict__ row_ptr) {
  if (threadIdx.x == 0 && blockIdx.x == 0) {
    int acc = 0;
    for (int b = 0; b < SCAN_B; ++b) { boff[b] = acc; acc += bsum[b]; }
    row_ptr[NN] = acc;
  }
}

__global__ __launch_bounds__(1024) void k_scan_apply(const int* __restrict__ cnt,
                                                     const int* __restrict__ boff,
                                                     int* __restrict__ row_ptr,
                                                     int* __restrict__ cursor) {
  __shared__ int sm[1024];
  int tid = threadIdx.x;
  int i = blockIdx.x * 1024 + tid;
  int v = (i < NN) ? cnt[i] : 0;
  sm[tid] = v;
  __syncthreads();
  for (int off = 1; off < 1024; off <<= 1) {
    int t = (tid >= off) ? sm[tid - off] : 0;
    __syncthreads();
    sm[tid] += t;
    __syncthreads();
  }
  int excl = boff[blockIdx.x] + sm[tid] - v;
  if (i < NN) { row_ptr[i] = excl; cursor[i] = excl; }
}

// ---------------- CSR fill: slot -> (src, edge) + dst ----------------
__global__ __launch_bounds__(256) void k_csrfill(const int* __restrict__ ei,
                                                 int* __restrict__ cursor,
                                                 int2* __restrict__ csr2,
                                                 int* __restrict__ csr_dst) {
  int e = blockIdx.x * 256 + threadIdx.x;
  if (e >= EE) return;
  int dst = ei[EE + e];
  int slot = atomicAdd(&cursor[dst], 1);
  csr2[slot] = make_int2(ei[e], e);
  csr_dst[slot] = dst;
}

// ---------------- per-node params ----------------
__global__ __launch_bounds__(256) void k_nodeparams(const int* __restrict__ cnt,
                                                    float* __restrict__ inv_deg,
                                                    float* __restrict__ s1a,
                                                    float* __restrict__ s2a) {
  int n = blockIdx.x * 256 + threadIdx.x;
  if (n >= NN) return;
  int c = cnt[n];
  float deg = (c > 0) ? (float)c : 1.0f;
  inv_deg[n] = 1.0f / deg;
  float logd = logf(deg + 1.0f);
  s1a[n] = logd / AVG_LOG;
  s2a[n] = AVG_LOG / logd;
}

// ---------------- per-layer weight composition + f16 pair packing ----------------
// wcpk[t][j][i2] : half2 (Wc[2*i2][j], Wc[2*i2+1][j])   i2 in [0,8)
// w2pk[t][j][i2] : half2 (W2[2*i2][j], W2[2*i2+1][j])   i2 in [0,10)
__global__ __launch_bounds__(64) void k_wcomb(const float* __restrict__ edge_w,
                                              const float* __restrict__ edge_b,
                                              const float* __restrict__ pre_w1,
                                              const float* __restrict__ pre_b1,
                                              const float* __restrict__ pre_w2,
                                              unsigned int* __restrict__ wcpk,
                                              unsigned int* __restrict__ w2pk,
                                              float* __restrict__ biasc, int l) {
  int t = blockIdx.x;
  int wt = l * TT + t;
  const float* W1 = pre_w1 + (size_t)wt * 1200; // [60][20]
  const float* W2 = pre_w2 + (size_t)wt * 400;  // [20][20]
  const float* ew = edge_w + (size_t)l * 16 * FF;
  const float* eb = edge_b + (size_t)l * FF;
  int j = threadIdx.x;
  if (j >= FF) return;
  float col[16];
  for (int i = 0; i < 16; ++i) {
    float acc = 0.f;
#pragma unroll
    for (int f = 0; f < FF; ++f) acc = fmaf(ew[i * FF + f], W1[(40 + f) * FF + j], acc);
    col[i] = acc;
  }
#pragma unroll
  for (int i2 = 0; i2 < 8; ++i2)
    wcpk[((size_t)t * FF + j) * 8 + i2] = packh2_rne(col[2 * i2], col[2 * i2 + 1]);
#pragma unroll
  for (int i2 = 0; i2 < 10; ++i2)
    w2pk[((size_t)t * FF + j) * 10 + i2] = packh2_rne(W2[(2 * i2) * FF + j], W2[(2 * i2 + 1) * FF + j]);
  float b = pre_b1[wt * FF + j];
#pragma unroll
  for (int f = 0; f < FF; ++f) b = fmaf(eb[f], W1[(40 + f) * FF + j], b);
  biasc[t * FF + j] = b;
}

// ---------------- post-MLP weight packing: Q1 rows [20,260) + Q2 as f16 pairs ----------------
// q1pk[t][i2][j], i2 in [0,120): pair k of view blk (blk=i2/40, k=i2%40) ->
//   rows (20+80*blk+2k, 20+80*blk+2k+1) of Q1.   q2pk[t][i2][j], i2 in [0,10).
__global__ __launch_bounds__(64) void k_postpk(const float* __restrict__ post_w1,
                                               const float* __restrict__ post_w2,
                                               unsigned int* __restrict__ q1pk,
                                               unsigned int* __restrict__ q2pk, int l) {
  int t = blockIdx.x;
  int wt = l * TT + t;
  const float* Q1 = post_w1 + (size_t)wt * 5200;
  const float* Q2 = post_w2 + (size_t)wt * 400;
  int j = threadIdx.x;
  if (j >= FF) return;
  for (int i2 = 0; i2 < 120; ++i2) {
    int blk = i2 / 40, k = i2 - blk * 40;
    int r0 = 20 + 80 * blk + 2 * k;
    q1pk[((size_t)t * 120 + i2) * FF + j] = packh2_rne(Q1[r0 * FF + j], Q1[(r0 + 1) * FF + j]);
  }
#pragma unroll
  for (int i2 = 0; i2 < 10; ++i2)
    q2pk[((size_t)t * 10 + i2) * FF + j] = packh2_rne(Q2[(2 * i2) * FF + j], Q2[(2 * i2 + 1) * FF + j]);
}

// ---------------- per-node pre contributions (bf16 out: halves gather bytes) ----------------
__global__ __launch_bounds__(256) void k_prenode(
    const float* __restrict__ h, const float* __restrict__ pre_w1,
    const float* __restrict__ biasc,
    unsigned short* __restrict__ predD, unsigned short* __restrict__ predS, int l) {
  int tid = threadIdx.x;
  int t = tid >> 6, lane = tid & 63;
  int n = blockIdx.x * 64 + lane;
  if (n >= NN) return;
  int wt_u = __builtin_amdgcn_readfirstlane(l * TT + t);
  const float* W1 = pre_w1 + (size_t)wt_u * 1200;
  const float* bc = biasc + t * FF;
  float xt[FF];
  {
    const float4* pp = (const float4*)(h + (size_t)n * DD + t * FF);
#pragma unroll
    for (int i = 0; i < 5; ++i) { float4 v = pp[i]; xt[i*4]=v.x; xt[i*4+1]=v.y; xt[i*4+2]=v.z; xt[i*4+3]=v.w; }
  }
  float d[FF], s[FF];
#pragma unroll
  for (int j = 0; j < FF; ++j) { d[j] = bc[j]; s[j] = 0.f; }
#pragma unroll
  for (int i = 0; i < FF; ++i) {
    float a = xt[i];
#pragma unroll
    for (int j = 0; j < FF; ++j) {
      d[j] = fmaf(a, W1[i * FF + j], d[j]);
      s[j] = fmaf(a, W1[(FF + i) * FF + j], s[j]);
    }
  }
  ushort4* pd = (ushort4*)(predD + (size_t)n * DD + t * FF);
  ushort4* ps = (ushort4*)(predS + (size_t)n * DD + t * FF);
#pragma unroll
  for (int i = 0; i < 5; ++i) {
    pd[i] = make_ushort4(f2bf(d[i*4]), f2bf(d[i*4+1]), f2bf(d[i*4+2]), f2bf(d[i*4+3]));
    ps[i] = make_ushort4(f2bf(s[i*4]), f2bf(s[i*4+1]), f2bf(s[i*4+2]), f2bf(s[i*4+3]));
  }
}

// ---------------- edge-parallel pre-MLP via v_dot2_f32_f16 ----------------
// m stored as f16 channel-pair dwords: row (t*10+pr) of capSlots dwords,
// m[(t*10+pr)*capSlots + sl] = half2(m2[2pr], m2[2pr+1]) of slot sl.
__global__ __launch_bounds__(256, 4) void k_pre(
    const unsigned short* __restrict__ predD, const unsigned short* __restrict__ predS,
    const float* __restrict__ edge_attr,
    const int2* __restrict__ csr2, const int* __restrict__ csr_dst,
    const int* __restrict__ row_ptr,
    const unsigned int* __restrict__ wcpk,
    const unsigned int* __restrict__ w2pk,
    const float* __restrict__ pre_b2,
    unsigned int* __restrict__ m, int l, int n0, int n1, int capSlots) {
  int tid = threadIdx.x;
  int t = tid >> 6;
  int lane = tid & 63;
  int wt_u = __builtin_amdgcn_readfirstlane(l * TT + t);
  int t_u  = __builtin_amdgcn_readfirstlane(t);
  const unsigned int* Wcp = wcpk + (size_t)t_u * FF * 8;   // [j][8]
  const unsigned int* W2p = w2pk + (size_t)t_u * FF * 10;  // [j][10]
  const float* b2 = pre_b2 + (size_t)wt_u * FF;

  int sl = blockIdx.x * 64 + lane;
  int base = row_ptr[n0], end = row_ptr[n1];
  if (sl >= capSlots || base + sl >= end) return;
  int p = base + sl;
  int2 se = csr2[p];
  int dst = csr_dst[p];

  float m1[FF];
  {
    const ushort4* pp = (const ushort4*)(predD + (size_t)dst * DD + t * FF);
    const ushort4* qq = (const ushort4*)(predS + (size_t)se.x * DD + t * FF);
#pragma unroll
    for (int i = 0; i < 5; ++i) {
      ushort4 u = pp[i];
      ushort4 v = qq[i];
      m1[i*4+0] = bf2f(u.x) + bf2f(v.x);
      m1[i*4+1] = bf2f(u.y) + bf2f(v.y);
      m1[i*4+2] = bf2f(u.z) + bf2f(v.z);
      m1[i*4+3] = bf2f(u.w) + bf2f(v.w);
    }
  }
  half2v eap[8];
  {
    const float4* ap = (const float4*)(edge_attr + (size_t)se.y * 16);
#pragma unroll
    for (int i = 0; i < 4; ++i) {
      float4 v = ap[i];
      eap[2*i]   = pkrtz(v.x, v.y);
      eap[2*i+1] = pkrtz(v.z, v.w);
    }
  }
  // GEMM1: m1[j] += ea[16] @ Wc[16][j]   (8 dot2 per channel)
#pragma unroll
  for (int j = 0; j < FF; ++j) {
    float c = m1[j];
#pragma unroll
    for (int i2 = 0; i2 < 8; ++i2) c = fdot2(eap[i2], u2h2(Wcp[j * 8 + i2]), c);
    m1[j] = c;
  }
  // relu + pack to half2 pairs
  half2v mp[10];
#pragma unroll
  for (int pr = 0; pr < 10; ++pr)
    mp[pr] = pkrtz(fmaxf(m1[2*pr], 0.f), fmaxf(m1[2*pr+1], 0.f));
  // GEMM2: m2[j] = b2[j] + relu(m1)[20] @ W2[20][j]  (10 dot2 per channel)
  float m2[FF];
#pragma unroll
  for (int j = 0; j < FF; ++j) {
    float c = b2[j];
#pragma unroll
    for (int i2 = 0; i2 < 10; ++i2) c = fdot2(mp[i2], u2h2(W2p[j * 10 + i2]), c);
    m2[j] = c;
  }
  unsigned int* mrow = m + (size_t)t * 10 * capSlots + sl;
#pragma unroll
  for (int pr = 0; pr < 10; ++pr)
    mrow[(size_t)pr * capSlots] = h22u(pkrtz(m2[2*pr], m2[2*pr+1]));
}

// ---------------- channel-pair-parallel aggregation (bf16 out) ----------------
// block = 320 threads = 32 nodes x 10 channel-pairs, one tower per block.
__global__ __launch_bounds__(320) void k_agg(
    const unsigned int* __restrict__ m,
    const int* __restrict__ row_ptr,
    const float* __restrict__ inv_deg,
    unsigned short* __restrict__ aggbuf, int n0, int n1, int capSlots) {
  int tid = threadIdx.x;
  int t = blockIdx.x & 3, tile = blockIdx.x >> 2;
  int ni = tid / 10, pr = tid - ni * 10;
  int n = n0 + tile * 32 + ni;
  if (n >= n1) return;
  int base = row_ptr[n0];
  int beg = row_ptr[n], end = row_ptr[n + 1];
  float inv = inv_deg[n];
  int s0 = beg - base, s1c = end - base;
  if (s0 < 0) s0 = 0;
  if (s1c > capSlots) s1c = capSlots;
  float sum0 = 0.f, sum1 = 0.f, sq0 = 0.f, sq1 = 0.f;
  float mn0 = 3.4e38f, mn1 = 3.4e38f, mx0 = -3.4e38f, mx1 = -3.4e38f;
  const unsigned int* mrow = m + (size_t)(t * 10 + pr) * capSlots;
  int p = s0;
  for (; p < s1c && (p & 3); ++p) {
    half2v h = u2h2(mrow[p]);
    float v0 = (float)h.x, v1 = (float)h.y;
    sum0 += v0; sq0 = fmaf(v0, v0, sq0); mn0 = fminf(mn0, v0); mx0 = fmaxf(mx0, v0);
    sum1 += v1; sq1 = fmaf(v1, v1, sq1); mn1 = fminf(mn1, v1); mx1 = fmaxf(mx1, v1);
  }
  for (; p + 4 <= s1c; p += 4) {
    uint4 q = *(const uint4*)(mrow + p);
#pragma unroll
    for (int k = 0; k < 4; ++k) {
      unsigned int u = (k == 0) ? q.x : (k == 1) ? q.y : (k == 2) ? q.z : q.w;
      half2v h = u2h2(u);
      float v0 = (float)h.x, v1 = (float)h.y;
      sum0 += v0; sq0 = fmaf(v0, v0, sq0); mn0 = fminf(mn0, v0); mx0 = fmaxf(mx0, v0);
      sum1 += v1; sq1 = fmaf(v1, v1, sq1); mn1 = fminf(mn1, v1); mx1 = fmaxf(mx1, v1);
    }
  }
  for (; p < s1c; ++p) {
    half2v h = u2h2(mrow[p]);
    float v0 = (float)h.x, v1 = (float)h.y;
    sum0 += v0; sq0 = fmaf(v0, v0, sq0); mn0 = fminf(mn0, v0); mx0 = fmaxf(mx0, v0);
    sum1 += v1; sq1 = fmaf(v1, v1, sq1); mn1 = fminf(mn1, v1); mx1 = fmaxf(mx1, v1);
  }
  float mu0 = sum0 * inv, mu1 = sum1 * inv;
  float sd0 = sqrtf(fmaxf(sq0 * inv - mu0 * mu0, 0.f) + 1e-5f);
  float sd1 = sqrtf(fmaxf(sq1 * inv - mu1 * mu1, 0.f) + 1e-5f);
  if (end <= beg) { mn0 = 0.f; mn1 = 0.f; mx0 = 0.f; mx1 = 0.f; }
  unsigned short* ab = aggbuf + ((size_t)(n - n0) * 4 + t) * 80;
  ((unsigned int*)(ab))[pr]      = pack_bf16(mu0, mu1);
  ((unsigned int*)(ab + 20))[pr] = pack_bf16(mn0, mn1);
  ((unsigned int*)(ab + 40))[pr] = pack_bf16(mx0, mx1);
  ((unsigned int*)(ab + 60))[pr] = pack_bf16(sd0, sd1);
}

// ---------------- node-parallel post-MLP via dot2, register-preloaded activations ----------------
// Single-tower blocks, tower-major grid (t = blockIdx/tiles) for scalar-cache locality.
__global__ __launch_bounds__(256) void k_post2(
    const float* __restrict__ h, const unsigned short* __restrict__ aggbuf,
    const float* __restrict__ s1a, const float* __restrict__ s2a,
    const float* __restrict__ post_w1, const float* __restrict__ post_b1,
    const unsigned int* __restrict__ q1pk, const unsigned int* __restrict__ q2pk,
    const float* __restrict__ post_b2,
    float* __restrict__ out2, int l, int n0, int n1, int tiles) {
  int t = blockIdx.x / tiles;          // block-uniform tower
  int tile = blockIdx.x - t * tiles;
  int wt_u = l * TT + t;
  const float* Q1 = post_w1 + (size_t)wt_u * 5200;  // fp32 rows [0,20) for xt part
  const float* B1 = post_b1 + (size_t)wt_u * FF;
  const float* B2 = post_b2 + (size_t)wt_u * FF;
  const unsigned int* q1 = q1pk + (size_t)t * 120 * FF;
  const unsigned int* q2 = q2pk + (size_t)t * 10 * FF;
  int n = n0 + tile * 256 + threadIdx.x;
  if (n >= n1) return;
  float c1 = s1a[n], c2 = s2a[n];
  half2v c1p = pkrtz(c1, c1), c2p = pkrtz(c2, c2);
  // preload h row (fp32)
  float xt[FF];
  {
    const float4* pp = (const float4*)(h + (size_t)n * DD + t * FF);
#pragma unroll
    for (int i = 0; i < 5; ++i) { float4 v = pp[i]; xt[i*4]=v.x; xt[i*4+1]=v.y; xt[i*4+2]=v.z; xt[i*4+3]=v.w; }
  }
  // preload agg row (80 bf16 = 10 uint4) -> 40 f16 pairs
  half2v a0p[40];
  {
    const uint4* ap = (const uint4*)(aggbuf + ((size_t)(n - n0) * 4 + t) * 80);
#pragma unroll
    for (int q = 0; q < 10; ++q) {
      uint4 v = ap[q];
      unsigned int w[4] = {v.x, v.y, v.z, v.w};
#pragma unroll
      for (int k = 0; k < 4; ++k) {
        unsigned int u = w[k];
        float lo = __uint_as_float(u << 16);
        float hi = __uint_as_float(u & 0xffff0000u);
        a0p[q * 4 + k] = pkrtz(lo, hi);
      }
    }
  }
  float o1[FF];
#pragma unroll
  for (int j = 0; j < FF; ++j) o1[j] = B1[j];
  // xt part, fp32 exact
#pragma unroll
  for (int i = 0; i < FF; ++i) {
    float a = xt[i];
#pragma unroll
    for (int j = 0; j < FF; ++j) o1[j] = fmaf(a, Q1[i * FF + j], o1[j]);
  }
  // a0 view
#pragma unroll 2
  for (int k = 0; k < 40; ++k) {
    half2v act = a0p[k];
    const unsigned int* wr = q1 + k * FF;
#pragma unroll
    for (int j = 0; j < FF; ++j) o1[j] = fdot2(act, u2h2(wr[j]), o1[j]);
  }
  // a1 = a0*c1 view
#pragma unroll 2
  for (int k = 0; k < 40; ++k) {
    half2v act = a0p[k] * c1p;
    const unsigned int* wr = q1 + (40 + k) * FF;
#pragma unroll
    for (int j = 0; j < FF; ++j) o1[j] = fdot2(act, u2h2(wr[j]), o1[j]);
  }
  // a2 = a0*c2 view
#pragma unroll 2
  for (int k = 0; k < 40; ++k) {
    half2v act = a0p[k] * c2p;
    const unsigned int* wr = q1 + (80 + k) * FF;
#pragma unroll
    for (int j = 0; j < FF; ++j) o1[j] = fdot2(act, u2h2(wr[j]), o1[j]);
  }
  // relu + pack, then GEMM2 via dot2
  half2v o1p[10];
#pragma unroll
  for (int i2 = 0; i2 < 10; ++i2)
    o1p[i2] = pkrtz(fmaxf(o1[2*i2], 0.f), fmaxf(o1[2*i2+1], 0.f));
  float o2[FF];
#pragma unroll
  for (int j = 0; j < FF; ++j) o2[j] = B2[j];
#pragma unroll 2
  for (int i2 = 0; i2 < 10; ++i2) {
    half2v act = o1p[i2];
    const unsigned int* wr = q2 + i2 * FF;
#pragma unroll
    for (int j = 0; j < FF; ++j) o2[j] = fdot2(act, u2h2(wr[j]), o2[j]);
  }
  float4* op = (float4*)(out2 + (size_t)n * DD + t * FF);
#pragma unroll
  for (int i = 0; i < 5; ++i) op[i] = make_float4(o2[i*4], o2[i*4+1], o2[i*4+2], o2[i*4+3]);
}

// ---------------- lin layer + BN column partial sums ----------------
__global__ __launch_bounds__(320) void k_lin(const float* __restrict__ out2,
                                             const float* __restrict__ lin_w,
                                             const float* __restrict__ lin_b,
                                             float* __restrict__ outl,
                                             float* __restrict__ colsum, int l) {
  __shared__ float Wl[DD * DD];
  __shared__ float rowbuf[4 * DD];
  __shared__ float red[320];
  int tid = threadIdx.x;
  for (int i = tid; i < DD * DD; i += 320) Wl[i] = lin_w[(size_t)l * DD * DD + i];
  __syncthreads();
  int nl = tid / DD, d = tid - nl * DD;
  float bias = lin_b[l * DD + d];
  float bsum = 0.f, bsq = 0.f;
  for (int base = blockIdx.x * 4; base < NN; base += gridDim.x * 4) {
    int gi = base * DD + tid;
    rowbuf[tid] = (gi < NN * DD) ? out2[gi] : 0.f;
    __syncthreads();
    int n = base + nl;
    if (n < NN) {
      float acc = bias;
#pragma unroll
      for (int i = 0; i < DD; ++i) acc = fmaf(rowbuf[nl * DD + i], Wl[i * DD + d], acc);
      outl[(size_t)n * DD + d] = acc;
      bsum += acc; bsq += acc * acc;
    }
    __syncthreads();
  }
  red[tid] = bsum;
  __syncthreads();
  if (tid < DD) {
    float s = red[tid] + red[tid + DD] + red[tid + 2 * DD] + red[tid + 3 * DD];
    atomicAdd(&colsum[d], s);
  }
  __syncthreads();
  red[tid] = bsq;
  __syncthreads();
  if (tid < DD) {
    float s = red[tid] + red[tid + DD] + red[tid + 2 * DD] + red[tid + 3 * DD];
    atomicAdd(&colsum[DD + d], s);
  }
}

// ---------------- BN finalize ----------------
__global__ __launch_bounds__(128) void k_bnfinal(const float* __restrict__ colsum,
                                                 const float* __restrict__ bn_g,
                                                 const float* __restrict__ bn_b,
                                                 float* __restrict__ bnsc, int l) {
  int d = threadIdx.x;
  if (d >= DD) return;
  float mu = colsum[d] * (1.0f / NN);
  float var = colsum[DD + d] * (1.0f / NN) - mu * mu;
  float sc = bn_g[l * DD + d] * rsqrtf(var + 1e-5f);
  bnsc[d] = sc;
  bnsc[DD + d] = bn_b[l * DD + d] - mu * sc;
}

// ---------------- BN apply + relu + residual into h ----------------
__global__ __launch_bounds__(256) void k_bnapply(const float* __restrict__ outl,
                                                 const float* __restrict__ bnsc,
                                                 float* __restrict__ h) {
  int idx = blockIdx.x * 256 + threadIdx.x;
  if (idx >= NN * DD) return;
  int d = idx % DD;
  float v = fmaf(outl[idx], bnsc[d], bnsc[DD + d]);
  h[idx] += fmaxf(v, 0.f);
}

// ---------------- graph pooling ----------------
__global__ __launch_bounds__(256) void k_gcnt(const int* __restrict__ batch, int* __restrict__ gcnt) {
  __shared__ int hcnt[GG];
  int tid = threadIdx.x;
  if (tid < GG) hcnt[tid] = 0;
  __syncthreads();
  int n = blockIdx.x * 256 + tid;
  if (n < NN) atomicAdd(&hcnt[batch[n]], 1);
  __syncthreads();
  if (tid < GG && hcnt[tid] > 0) atomicAdd(&gcnt[tid], hcnt[tid]);
}

__global__ void k_gstart(const int* __restrict__ gcnt, int* __restrict__ gstart) {
  if (threadIdx.x == 0 && blockIdx.x == 0) {
    int acc = 0;
    for (int g = 0; g < GG; ++g) { gstart[g] = acc; acc += gcnt[g]; }
  }
}

__global__ __launch_bounds__(320) void k_gmean(const float* __restrict__ h,
                                               const int* __restrict__ gstart,
                                               const int* __restrict__ gcnt,
                                               float* __restrict__ gbuf) {
  __shared__ float red[320];
  int g = blockIdx.x, tid = threadIdx.x;
  int nl = tid / DD, d = tid - nl * DD;
  int start = gstart[g], c = gcnt[g];
  float acc = 0.f;
  for (int r = start + nl; r < start + c; r += 4) acc += h[(size_t)r * DD + d];
  red[tid] = acc;
  __syncthreads();
  if (tid < DD) {
    float s = red[tid] + red[tid + DD] + red[tid + 2 * DD] + red[tid + 3 * DD];
    float cf = (c > 0) ? (float)c : 1.0f;
    gbuf[g * DD + tid] = s / cf;
  }
}

// ---------------- final MLP (tiny) ----------------
__global__ __launch_bounds__(64) void k_mlp(const float* __restrict__ gbuf,
                                            const float* __restrict__ w1, const float* __restrict__ b1,
                                            const float* __restrict__ w2, const float* __restrict__ b2,
                                            const float* __restrict__ w3, const float* __restrict__ b3,
                                            float* __restrict__ out) {
  __shared__ float row[DD];
  __shared__ float t1[40];
  __shared__ float t2[20];
  int g = blockIdx.x, tid = threadIdx.x;
  for (int i = tid; i < DD; i += 64) row[i] = gbuf[g * DD + i];
  __syncthreads();
  if (tid < 40) {
    float acc = b1[tid];
#pragma unroll
    for (int i = 0; i < DD; ++i) acc = fmaf(row[i], w1[i * 40 + tid], acc);
    t1[tid] = fmaxf(acc, 0.f);
  }
  __syncthreads();
  if (tid < 20) {
    float acc = b2[tid];
#pragma unroll
    for (int i = 0; i < 40; ++i) acc = fmaf(t1[i], w2[i * 20 + tid], acc);
    t2[tid] = fmaxf(acc, 0.f);
  }
  __syncthreads();
  if (tid == 0) {
    float acc = b3[0];
#pragma unroll
    for (int i = 0; i < 20; ++i) acc = fmaf(t2[i], w3[i], acc);
    out[g] = acc;
  }
}

extern "C" void kernel_launch(void* const* d_in, const int* in_sizes, int n_in,
                              void* d_out, int out_size, void* d_ws, size_t ws_size,
                              hipStream_t stream) {
  const int*   x         = (const int*)d_in[0];
  const int*   ei        = (const int*)d_in[1];
  const int*   batch     = (const int*)d_in[2];
  const float* edge_attr = (const float*)d_in[3];
  const float* atom_emb  = (const float*)d_in[4];
  const float* edge_w    = (const float*)d_in[5];
  const float* edge_b    = (const float*)d_in[6];
  const float* pre_w1    = (const float*)d_in[7];
  const float* pre_b1    = (const float*)d_in[8];
  const float* pre_w2    = (const float*)d_in[9];
  const float* pre_b2    = (const float*)d_in[10];
  const float* post_w1   = (const float*)d_in[11];
  const float* post_b1   = (const float*)d_in[12];
  const float* post_w2   = (const float*)d_in[13];
  const float* post_b2   = (const float*)d_in[14];
  const float* lin_w     = (const float*)d_in[15];
  const float* lin_b     = (const float*)d_in[16];
  const float* bn_g      = (const float*)d_in[17];
  const float* bn_b      = (const float*)d_in[18];
  const float* mlp_w1    = (const float*)d_in[19];
  const float* mlp_b1    = (const float*)d_in[20];
  const float* mlp_w2    = (const float*)d_in[21];
  const float* mlp_b2    = (const float*)d_in[22];
  const float* mlp_w3    = (const float*)d_in[23];
  const float* mlp_b3    = (const float*)d_in[24];
  float* out = (float*)d_out;

  // workspace carve-up — MUST stay within ws_size
  char* ws = (char*)d_ws;
  size_t off = 0;
  auto alloc = [&](size_t bytes) -> void* {
    void* p = ws + off;
    off += (bytes + 15) & ~(size_t)15;
    return p;
  };
  float* h       = (float*)alloc((size_t)NN * DD * 4);           // 16 MB
  float* out2    = (float*)alloc((size_t)NN * DD * 4);           // 16 MB
  unsigned short* predD = (unsigned short*)alloc((size_t)NN * DD * 2); // 8 MB bf16
  unsigned short* predS = (unsigned short*)alloc((size_t)NN * DD * 2); // 8 MB bf16
  int2*  csr2    = (int2*)alloc((size_t)EE * 8);                 // 6.4 MB
  int*   csr_dst = (int*)alloc((size_t)EE * 4);                  // 3.2 MB
  int*   row_ptr = (int*)alloc((size_t)(NN + 1) * 4);
  int*   cnt     = (int*)alloc((size_t)NN * 4);
  int*   cursor  = (int*)alloc((size_t)NN * 4);
  float* inv_deg = (float*)alloc((size_t)NN * 4);
  float* s1a     = (float*)alloc((size_t)NN * 4);
  float* s2a     = (float*)alloc((size_t)NN * 4);
  float* colsum  = (float*)alloc(2 * DD * 4);
  float* bnsc    = (float*)alloc(2 * DD * 4);
  float* gbuf    = (float*)alloc((size_t)GG * DD * 4);
  unsigned int* wcpk  = (unsigned int*)alloc((size_t)TT * FF * 8 * 4);
  unsigned int* w2pk  = (unsigned int*)alloc((size_t)TT * FF * 10 * 4);
  unsigned int* q1pk  = (unsigned int*)alloc((size_t)TT * 120 * FF * 4);
  unsigned int* q2pk  = (unsigned int*)alloc((size_t)TT * 10 * FF * 4);
  float* biasc   = (float*)alloc((size_t)TT * FF * 4);
  int*   bsum    = (int*)alloc((size_t)SCAN_B * 4);
  int*   boff    = (int*)alloc((size_t)SCAN_B * 4);
  int*   gcnt    = (int*)alloc((size_t)GG * 4);
  int*   gstart  = (int*)alloc((size_t)(GG + 1) * 4);
  (void)in_sizes; (void)n_in; (void)out_size;

  // remainder -> aggbuf (bf16 stats) + f16 m chunk buffer; outl aliases region.
  size_t rest = (ws_size > off) ? (ws_size - off) : 0;
  static const int cands[] = {1, 2, 4, 5, 8, 10, 20, 25, 40, 50};
  int c = -1, capSlots = 0, nodesPer = 0;
  size_t aggBytes = 0;
  for (int ci = 0; ci < 10; ++ci) {
    int cc = cands[ci];
    int np = (NN + cc - 1) / cc;
    size_t ab = ((size_t)np * 4 * 80 * 2 + 63) & ~(size_t)63;    // bf16 stats
    int slots = EE / cc + 25000; if (slots > EE) slots = EE;
    slots = (slots + 63) & ~63;
    size_t mb = (size_t)slots * DD * 2;                          // f16: 40 dword rows
    if (ab + mb <= rest && ab + mb >= (size_t)NN * DD * 4) {     // outl (16 MB) must fit alias
      c = cc; capSlots = slots; nodesPer = np; aggBytes = ab;
      break;
    }
  }
  if (c < 0) { // degenerate fallback
    c = 50; nodesPer = (NN + c - 1) / c;
    aggBytes = ((size_t)nodesPer * 4 * 80 * 2 + 63) & ~(size_t)63;
    size_t mb = (rest > aggBytes) ? rest - aggBytes : 0;
    capSlots = (int)(mb / (DD * 2)) & ~63;
  }
  unsigned short* aggbuf = (unsigned short*)(ws + off);
  unsigned int* mbuf = (unsigned int*)(ws + off + aggBytes);
  float* outl = (float*)(ws + off); // alias: k_lin runs after all chunks of the layer

  hipMemsetAsync(cnt, 0, (size_t)NN * 4, stream);
  k_h<<<(NN * DD + 255) / 256, 256, 0, stream>>>(x, atom_emb, h);
  k_deg<<<(EE + 255) / 256, 256, 0, stream>>>(ei, cnt);
  k_scan_sum<<<SCAN_B, 1024, 0, stream>>>(cnt, bsum);
  k_scan_top<<<1, 64, 0, stream>>>(bsum, boff, row_ptr);
  k_scan_apply<<<SCAN_B, 1024, 0, stream>>>(cnt, boff, row_ptr, cursor);
  k_csrfill<<<(EE + 255) / 256, 256, 0, stream>>>(ei, cursor, csr2, csr_dst);
  k_nodeparams<<<(NN + 255) / 256, 256, 0, stream>>>(cnt, inv_deg, s1a, s2a);

  for (int l = 0; l < LL; ++l) {
    k_wcomb<<<TT, 64, 0, stream>>>(edge_w, edge_b, pre_w1, pre_b1, pre_w2, wcpk, w2pk, biasc, l);
    k_postpk<<<TT, 64, 0, stream>>>(post_w1, post_w2, q1pk, q2pk, l);
    k_prenode<<<(NN + 63) / 64, 256, 0, stream>>>(h, pre_w1, biasc, predD, predS, l);
    for (int ck = 0; ck < c; ++ck) {
      int n0 = ck * nodesPer;
      int n1 = n0 + nodesPer; if (n1 > NN) n1 = NN;
      if (n0 >= n1) continue;
      int preBlocks = (capSlots + 63) / 64;
      k_pre<<<preBlocks, 256, 0, stream>>>(predD, predS, edge_attr, csr2, csr_dst, row_ptr,
          wcpk, w2pk, pre_b2, mbuf, l, n0, n1, capSlots);
      int aggBlocks = ((n1 - n0 + 31) / 32) * 4;
      k_agg<<<aggBlocks, 320, 0, stream>>>(mbuf, row_ptr, inv_deg, aggbuf, n0, n1, capSlots);
      int tiles = (n1 - n0 + 255) / 256;
      k_post2<<<tiles * TT, 256, 0, stream>>>(h, aggbuf, s1a, s2a,
          post_w1, post_b1, q1pk, q2pk, post_b2, out2, l, n0, n1, tiles);
    }
    hipMemsetAsync(colsum, 0, 2 * DD * 4, stream);
    k_lin<<<512, 320, 0, stream>>>(out2, lin_w, lin_b, outl, colsum, l);
    k_bnfinal<<<1, 128, 0, stream>>>(colsum, bn_g, bn_b, bnsc, l);
    k_bnapply<<<(NN * DD + 255) / 256, 256, 0, stream>>>(outl, bnsc, h);
  }

  hipMemsetAsync(gcnt, 0, (size_t)GG * 4, stream);
  k_gcnt<<<(NN + 255) / 256, 256, 0, stream>>>(batch, gcnt);
  k_gstart<<<1, 64, 0, stream>>>(gcnt, gstart);
  k_gmean<<<GG, 320, 0, stream>>>(h, gstart, gcnt, gbuf);
  k_mlp<<<GG, 64, 0, stream>>>(gbuf, mlp_w1, mlp_b1, mlp_w2, mlp_b2, mlp_w3, mlp_b3, out);
}

// Round 5
// 1492.263 us; speedup vs baseline: 1.0696x; 1.0696x over previous
//
#include <hip/hip_runtime.h>
#include <hip/hip_bf16.h>

// Problem constants (from reference)
#define NN 50000
#define EE 800000
#define GG 128
#define LL 4
#define TT 4
#define FF 20
#define DD 80
#define SCAN_B ((NN + 1023) / 1024)   // 49
static constexpr float AVG_LOG = 2.8332133440562162f; // ln(17)

typedef __fp16 half2v __attribute__((ext_vector_type(2)));

__device__ __forceinline__ float bf2f(unsigned short u) {
  return __uint_as_float((unsigned)u << 16);
}
__device__ __forceinline__ unsigned short f2bf(float f) {
  __hip_bfloat16 b = __float2bfloat16(f); // RNE
  return *(unsigned short*)&b;
}
__device__ __forceinline__ half2v pkrtz(float a, float b) {
#if __has_builtin(__builtin_amdgcn_cvt_pkrtz)
  return __builtin_amdgcn_cvt_pkrtz(a, b);
#else
  half2v h; h.x = (__fp16)a; h.y = (__fp16)b; return h;
#endif
}
__device__ __forceinline__ float fdot2(half2v a, half2v b, float c) {
#if __has_builtin(__builtin_amdgcn_fdot2)
  return __builtin_amdgcn_fdot2(a, b, c, false);
#else
  return fmaf((float)a.x, (float)b.x, fmaf((float)a.y, (float)b.y, c));
#endif
}
__device__ __forceinline__ half2v u2h2(unsigned int u) {
  return __builtin_bit_cast(half2v, u);
}
__device__ __forceinline__ unsigned int h22u(half2v h) {
  return __builtin_bit_cast(unsigned int, h);
}
__device__ __forceinline__ unsigned int packh2_rne(float a, float b) {
  half2v h; h.x = (__fp16)a; h.y = (__fp16)b; // RNE casts for weights
  return h22u(h);
}
__device__ __forceinline__ unsigned int pack_bf16(float a, float b) {
  return (unsigned int)f2bf(a) | ((unsigned int)f2bf(b) << 16);
}

// ---------------- h init: h[n,d] = sum_i atom_emb[i, x[n,i], d] ----------------
__global__ __launch_bounds__(256) void k_h(const int* __restrict__ x,
                                           const float* __restrict__ atom_emb,
                                           float* __restrict__ h) {
  int idx = blockIdx.x * 256 + threadIdx.x;
  if (idx >= NN * DD) return;
  int n = idx / DD, d = idx - n * DD;
  const int* xr = x + n * 9;
  float acc = 0.f;
#pragma unroll
  for (int i = 0; i < 9; ++i) {
    int v = xr[i];
    acc += atom_emb[(i * 16 + v) * DD + d];
  }
  h[idx] = acc;
}

// ---------------- degree count ----------------
__global__ __launch_bounds__(256) void k_deg(const int* __restrict__ ei, int* __restrict__ cnt) {
  int e = blockIdx.x * 256 + threadIdx.x;
  if (e >= EE) return;
  atomicAdd(&cnt[ei[EE + e]], 1); // dst = edge_index[1][e]
}

// ---------------- hierarchical exclusive scan ----------------
__global__ __launch_bounds__(1024) void k_scan_sum(const int* __restrict__ cnt, int* __restrict__ bsum) {
  __shared__ int red[1024];
  int tid = threadIdx.x;
  int i = blockIdx.x * 1024 + tid;
  red[tid] = (i < NN) ? cnt[i] : 0;
  __syncthreads();
  for (int off = 512; off > 0; off >>= 1) {
    if (tid < off) red[tid] += red[tid + off];
    __syncthreads();
  }
  if (tid == 0) bsum[blockIdx.x] = red[0];
}

__global__ void k_scan_top(const int* __restrict__ bsum, int* __restrict__ boff,
                           int* __restrict__ row_ptr) {
  if (threadIdx.x == 0 && blockIdx.x == 0) {
    int acc = 0;
    for (int b = 0; b < SCAN_B; ++b) { boff[b] = acc; acc += bsum[b]; }
    row_ptr[NN] = acc;
  }
}

__global__ __launch_bounds__(1024) void k_scan_apply(const int* __restrict__ cnt,
                                                     const int* __restrict__ boff,
                                                     int* __restrict__ row_ptr,
                                                     int* __restrict__ cursor) {
  __shared__ int sm[1024];
  int tid = threadIdx.x;
  int i = blockIdx.x * 1024 + tid;
  int v = (i < NN) ? cnt[i] : 0;
  sm[tid] = v;
  __syncthreads();
  for (int off = 1; off < 1024; off <<= 1) {
    int t = (tid >= off) ? sm[tid - off] : 0;
    __syncthreads();
    sm[tid] += t;
    __syncthreads();
  }
  int excl = boff[blockIdx.x] + sm[tid] - v;
  if (i < NN) { row_ptr[i] = excl; cursor[i] = excl; }
}

// ---------------- CSR fill: slot -> (src, edge) + dst ----------------
__global__ __launch_bounds__(256) void k_csrfill(const int* __restrict__ ei,
                                                 int* __restrict__ cursor,
                                                 int2* __restrict__ csr2,
                                                 int* __restrict__ csr_dst) {
  int e = blockIdx.x * 256 + threadIdx.x;
  if (e >= EE) return;
  int dst = ei[EE + e];
  int slot = atomicAdd(&cursor[dst], 1);
  csr2[slot] = make_int2(ei[e], e);
  csr_dst[slot] = dst;
}

// ---------------- one-time edge_attr gather into CSR slot order, f16 pairs ----------------
// ea16[slot][i2] = half2(edge_attr[e][2*i2], edge_attr[e][2*i2+1]), i2 in [0,8)
__global__ __launch_bounds__(256) void k_eagather(const int2* __restrict__ csr2,
                                                  const float* __restrict__ edge_attr,
                                                  unsigned int* __restrict__ ea16) {
  int sl = blockIdx.x * 256 + threadIdx.x;
  if (sl >= EE) return;
  int e = csr2[sl].y;
  const float4* ap = (const float4*)(edge_attr + (size_t)e * 16);
  uint4 o0, o1;
  float4 v0 = ap[0], v1 = ap[1], v2 = ap[2], v3 = ap[3];
  o0.x = packh2_rne(v0.x, v0.y); o0.y = packh2_rne(v0.z, v0.w);
  o0.z = packh2_rne(v1.x, v1.y); o0.w = packh2_rne(v1.z, v1.w);
  o1.x = packh2_rne(v2.x, v2.y); o1.y = packh2_rne(v2.z, v2.w);
  o1.z = packh2_rne(v3.x, v3.y); o1.w = packh2_rne(v3.z, v3.w);
  uint4* op = (uint4*)(ea16 + (size_t)sl * 8);
  op[0] = o0; op[1] = o1;
}

// ---------------- per-node params ----------------
__global__ __launch_bounds__(256) void k_nodeparams(const int* __restrict__ cnt,
                                                    float* __restrict__ inv_deg,
                                                    float* __restrict__ s1a,
                                                    float* __restrict__ s2a) {
  int n = blockIdx.x * 256 + threadIdx.x;
  if (n >= NN) return;
  int c = cnt[n];
  float deg = (c > 0) ? (float)c : 1.0f;
  inv_deg[n] = 1.0f / deg;
  float logd = logf(deg + 1.0f);
  s1a[n] = logd / AVG_LOG;
  s2a[n] = AVG_LOG / logd;
}

// ---------------- per-layer weight composition + f16 pair packing ----------------
// wcpk[t][j][i2] : half2 (Wc[2*i2][j], Wc[2*i2+1][j])   i2 in [0,8)
// w2pk[t][j][i2] : half2 (W2[2*i2][j], W2[2*i2+1][j])   i2 in [0,10)
__global__ __launch_bounds__(64) void k_wcomb(const float* __restrict__ edge_w,
                                              const float* __restrict__ edge_b,
                                              const float* __restrict__ pre_w1,
                                              const float* __restrict__ pre_b1,
                                              const float* __restrict__ pre_w2,
                                              unsigned int* __restrict__ wcpk,
                                              unsigned int* __restrict__ w2pk,
                                              float* __restrict__ biasc, int l) {
  int t = blockIdx.x;
  int wt = l * TT + t;
  const float* W1 = pre_w1 + (size_t)wt * 1200; // [60][20]
  const float* W2 = pre_w2 + (size_t)wt * 400;  // [20][20]
  const float* ew = edge_w + (size_t)l * 16 * FF;
  const float* eb = edge_b + (size_t)l * FF;
  int j = threadIdx.x;
  if (j >= FF) return;
  float col[16];
  for (int i = 0; i < 16; ++i) {
    float acc = 0.f;
#pragma unroll
    for (int f = 0; f < FF; ++f) acc = fmaf(ew[i * FF + f], W1[(40 + f) * FF + j], acc);
    col[i] = acc;
  }
#pragma unroll
  for (int i2 = 0; i2 < 8; ++i2)
    wcpk[((size_t)t * FF + j) * 8 + i2] = packh2_rne(col[2 * i2], col[2 * i2 + 1]);
#pragma unroll
  for (int i2 = 0; i2 < 10; ++i2)
    w2pk[((size_t)t * FF + j) * 10 + i2] = packh2_rne(W2[(2 * i2) * FF + j], W2[(2 * i2 + 1) * FF + j]);
  float b = pre_b1[wt * FF + j];
#pragma unroll
  for (int f = 0; f < FF; ++f) b = fmaf(eb[f], W1[(40 + f) * FF + j], b);
  biasc[t * FF + j] = b;
}

// ---------------- post-MLP weight packing: Q1 rows [20,260) + Q2 as f16 pairs ----------------
__global__ __launch_bounds__(64) void k_postpk(const float* __restrict__ post_w1,
                                               const float* __restrict__ post_w2,
                                               unsigned int* __restrict__ q1pk,
                                               unsigned int* __restrict__ q2pk, int l) {
  int t = blockIdx.x;
  int wt = l * TT + t;
  const float* Q1 = post_w1 + (size_t)wt * 5200;
  const float* Q2 = post_w2 + (size_t)wt * 400;
  int j = threadIdx.x;
  if (j >= FF) return;
  for (int i2 = 0; i2 < 120; ++i2) {
    int blk = i2 / 40, k = i2 - blk * 40;
    int r0 = 20 + 80 * blk + 2 * k;
    q1pk[((size_t)t * 120 + i2) * FF + j] = packh2_rne(Q1[r0 * FF + j], Q1[(r0 + 1) * FF + j]);
  }
#pragma unroll
  for (int i2 = 0; i2 < 10; ++i2)
    q2pk[((size_t)t * 10 + i2) * FF + j] = packh2_rne(Q2[(2 * i2) * FF + j], Q2[(2 * i2 + 1) * FF + j]);
}

// ---------------- per-node pre contributions (bf16 out: halves gather bytes) ----------------
__global__ __launch_bounds__(256) void k_prenode(
    const float* __restrict__ h, const float* __restrict__ pre_w1,
    const float* __restrict__ biasc,
    unsigned short* __restrict__ predD, unsigned short* __restrict__ predS, int l) {
  int tid = threadIdx.x;
  int t = tid >> 6, lane = tid & 63;
  int n = blockIdx.x * 64 + lane;
  if (n >= NN) return;
  int wt_u = __builtin_amdgcn_readfirstlane(l * TT + t);
  const float* W1 = pre_w1 + (size_t)wt_u * 1200;
  const float* bc = biasc + t * FF;
  float xt[FF];
  {
    const float4* pp = (const float4*)(h + (size_t)n * DD + t * FF);
#pragma unroll
    for (int i = 0; i < 5; ++i) { float4 v = pp[i]; xt[i*4]=v.x; xt[i*4+1]=v.y; xt[i*4+2]=v.z; xt[i*4+3]=v.w; }
  }
  float d[FF], s[FF];
#pragma unroll
  for (int j = 0; j < FF; ++j) { d[j] = bc[j]; s[j] = 0.f; }
#pragma unroll
  for (int i = 0; i < FF; ++i) {
    float a = xt[i];
#pragma unroll
    for (int j = 0; j < FF; ++j) {
      d[j] = fmaf(a, W1[i * FF + j], d[j]);
      s[j] = fmaf(a, W1[(FF + i) * FF + j], s[j]);
    }
  }
  ushort4* pd = (ushort4*)(predD + (size_t)n * DD + t * FF);
  ushort4* ps = (ushort4*)(predS + (size_t)n * DD + t * FF);
#pragma unroll
  for (int i = 0; i < 5; ++i) {
    pd[i] = make_ushort4(f2bf(d[i*4]), f2bf(d[i*4+1]), f2bf(d[i*4+2]), f2bf(d[i*4+3]));
    ps[i] = make_ushort4(f2bf(s[i*4]), f2bf(s[i*4+1]), f2bf(s[i*4+2]), f2bf(s[i*4+3]));
  }
}

// ---------------- edge-parallel pre-MLP via v_dot2_f32_f16 ----------------
// ea read from pre-gathered CSR-ordered f16 buffer (coalesced, 32 B/edge).
__global__ __launch_bounds__(256, 4) void k_pre(
    const unsigned short* __restrict__ predD, const unsigned short* __restrict__ predS,
    const unsigned int* __restrict__ ea16,
    const int2* __restrict__ csr2, const int* __restrict__ csr_dst,
    const int* __restrict__ row_ptr,
    const unsigned int* __restrict__ wcpk,
    const unsigned int* __restrict__ w2pk,
    const float* __restrict__ pre_b2,
    unsigned int* __restrict__ m, int l, int n0, int n1, int capSlots) {
  int tid = threadIdx.x;
  int t = tid >> 6;
  int lane = tid & 63;
  int wt_u = __builtin_amdgcn_readfirstlane(l * TT + t);
  int t_u  = __builtin_amdgcn_readfirstlane(t);
  const unsigned int* Wcp = wcpk + (size_t)t_u * FF * 8;   // [j][8]
  const unsigned int* W2p = w2pk + (size_t)t_u * FF * 10;  // [j][10]
  const float* b2 = pre_b2 + (size_t)wt_u * FF;

  int sl = blockIdx.x * 64 + lane;
  int base = row_ptr[n0], end = row_ptr[n1];
  if (sl >= capSlots || base + sl >= end) return;
  int p = base + sl;
  int src = csr2[p].x;
  int dst = csr_dst[p];

  float m1[FF];
  {
    const ushort4* pp = (const ushort4*)(predD + (size_t)dst * DD + t * FF);
    const ushort4* qq = (const ushort4*)(predS + (size_t)src * DD + t * FF);
#pragma unroll
    for (int i = 0; i < 5; ++i) {
      ushort4 u = pp[i];
      ushort4 v = qq[i];
      m1[i*4+0] = bf2f(u.x) + bf2f(v.x);
      m1[i*4+1] = bf2f(u.y) + bf2f(v.y);
      m1[i*4+2] = bf2f(u.z) + bf2f(v.z);
      m1[i*4+3] = bf2f(u.w) + bf2f(v.w);
    }
  }
  half2v eap[8];
  {
    const uint4* ep = (const uint4*)(ea16 + (size_t)p * 8);
    uint4 e0 = ep[0], e1 = ep[1];
    eap[0] = u2h2(e0.x); eap[1] = u2h2(e0.y); eap[2] = u2h2(e0.z); eap[3] = u2h2(e0.w);
    eap[4] = u2h2(e1.x); eap[5] = u2h2(e1.y); eap[6] = u2h2(e1.z); eap[7] = u2h2(e1.w);
  }
  // GEMM1: m1[j] += ea[16] @ Wc[16][j]   (8 dot2 per channel)
#pragma unroll
  for (int j = 0; j < FF; ++j) {
    float c = m1[j];
#pragma unroll
    for (int i2 = 0; i2 < 8; ++i2) c = fdot2(eap[i2], u2h2(Wcp[j * 8 + i2]), c);
    m1[j] = c;
  }
  // relu + pack to half2 pairs
  half2v mp[10];
#pragma unroll
  for (int pr = 0; pr < 10; ++pr)
    mp[pr] = pkrtz(fmaxf(m1[2*pr], 0.f), fmaxf(m1[2*pr+1], 0.f));
  // GEMM2: m2[j] = b2[j] + relu(m1)[20] @ W2[20][j]  (10 dot2 per channel)
  float m2[FF];
#pragma unroll
  for (int j = 0; j < FF; ++j) {
    float c = b2[j];
#pragma unroll
    for (int i2 = 0; i2 < 10; ++i2) c = fdot2(mp[i2], u2h2(W2p[j * 10 + i2]), c);
    m2[j] = c;
  }
  unsigned int* mrow = m + (size_t)t * 10 * capSlots + sl;
#pragma unroll
  for (int pr = 0; pr < 10; ++pr)
    mrow[(size_t)pr * capSlots] = h22u(pkrtz(m2[2*pr], m2[2*pr+1]));
}

// ---------------- channel-pair-parallel aggregation (bf16 out) ----------------
// block = 320 threads = 32 nodes x 10 channel-pairs, one tower per block.
__global__ __launch_bounds__(320) void k_agg(
    const unsigned int* __restrict__ m,
    const int* __restrict__ row_ptr,
    const float* __restrict__ inv_deg,
    unsigned short* __restrict__ aggbuf, int n0, int n1, int capSlots) {
  int tid = threadIdx.x;
  int t = blockIdx.x & 3, tile = blockIdx.x >> 2;
  int ni = tid / 10, pr = tid - ni * 10;
  int n = n0 + tile * 32 + ni;
  if (n >= n1) return;
  int base = row_ptr[n0];
  int beg = row_ptr[n], end = row_ptr[n + 1];
  float inv = inv_deg[n];
  int s0 = beg - base, s1c = end - base;
  if (s0 < 0) s0 = 0;
  if (s1c > capSlots) s1c = capSlots;
  float sum0 = 0.f, sum1 = 0.f, sq0 = 0.f, sq1 = 0.f;
  float mn0 = 3.4e38f, mn1 = 3.4e38f, mx0 = -3.4e38f, mx1 = -3.4e38f;
  const unsigned int* mrow = m + (size_t)(t * 10 + pr) * capSlots;
  int p = s0;
  for (; p < s1c && (p & 3); ++p) {
    half2v h = u2h2(mrow[p]);
    float v0 = (float)h.x, v1 = (float)h.y;
    sum0 += v0; sq0 = fmaf(v0, v0, sq0); mn0 = fminf(mn0, v0); mx0 = fmaxf(mx0, v0);
    sum1 += v1; sq1 = fmaf(v1, v1, sq1); mn1 = fminf(mn1, v1); mx1 = fmaxf(mx1, v1);
  }
  for (; p + 4 <= s1c; p += 4) {
    uint4 q = *(const uint4*)(mrow + p);
#pragma unroll
    for (int k = 0; k < 4; ++k) {
      unsigned int u = (k == 0) ? q.x : (k == 1) ? q.y : (k == 2) ? q.z : q.w;
      half2v h = u2h2(u);
      float v0 = (float)h.x, v1 = (float)h.y;
      sum0 += v0; sq0 = fmaf(v0, v0, sq0); mn0 = fminf(mn0, v0); mx0 = fmaxf(mx0, v0);
      sum1 += v1; sq1 = fmaf(v1, v1, sq1); mn1 = fminf(mn1, v1); mx1 = fmaxf(mx1, v1);
    }
  }
  for (; p < s1c; ++p) {
    half2v h = u2h2(mrow[p]);
    float v0 = (float)h.x, v1 = (float)h.y;
    sum0 += v0; sq0 = fmaf(v0, v0, sq0); mn0 = fminf(mn0, v0); mx0 = fmaxf(mx0, v0);
    sum1 += v1; sq1 = fmaf(v1, v1, sq1); mn1 = fminf(mn1, v1); mx1 = fmaxf(mx1, v1);
  }
  float mu0 = sum0 * inv, mu1 = sum1 * inv;
  float sd0 = sqrtf(fmaxf(sq0 * inv - mu0 * mu0, 0.f) + 1e-5f);
  float sd1 = sqrtf(fmaxf(sq1 * inv - mu1 * mu1, 0.f) + 1e-5f);
  if (end <= beg) { mn0 = 0.f; mn1 = 0.f; mx0 = 0.f; mx1 = 0.f; }
  unsigned short* ab = aggbuf + ((size_t)(n - n0) * 4 + t) * 80;
  ((unsigned int*)(ab))[pr]      = pack_bf16(mu0, mu1);
  ((unsigned int*)(ab + 20))[pr] = pack_bf16(mn0, mn1);
  ((unsigned int*)(ab + 40))[pr] = pack_bf16(mx0, mx1);
  ((unsigned int*)(ab + 60))[pr] = pack_bf16(sd0, sd1);
}

// ---------------- node-parallel post-MLP via dot2, register-preloaded activations ----------------
__global__ __launch_bounds__(256) void k_post2(
    const float* __restrict__ h, const unsigned short* __restrict__ aggbuf,
    const float* __restrict__ s1a, const float* __restrict__ s2a,
    const float* __restrict__ post_w1, const float* __restrict__ post_b1,
    const unsigned int* __restrict__ q1pk, const unsigned int* __restrict__ q2pk,
    const float* __restrict__ post_b2,
    float* __restrict__ out2, int l, int n0, int n1, int tiles) {
  int t = blockIdx.x / tiles;          // block-uniform tower
  int tile = blockIdx.x - t * tiles;
  int wt_u = l * TT + t;
  const float* Q1 = post_w1 + (size_t)wt_u * 5200;  // fp32 rows [0,20) for xt part
  const float* B1 = post_b1 + (size_t)wt_u * FF;
  const float* B2 = post_b2 + (size_t)wt_u * FF;
  const unsigned int* q1 = q1pk + (size_t)t * 120 * FF;
  const unsigned int* q2 = q2pk + (size_t)t * 10 * FF;
  int n = n0 + tile * 256 + threadIdx.x;
  if (n >= n1) return;
  float c1 = s1a[n], c2 = s2a[n];
  half2v c1p = pkrtz(c1, c1), c2p = pkrtz(c2, c2);
  // preload h row (fp32)
  float xt[FF];
  {
    const float4* pp = (const float4*)(h + (size_t)n * DD + t * FF);
#pragma unroll
    for (int i = 0; i < 5; ++i) { float4 v = pp[i]; xt[i*4]=v.x; xt[i*4+1]=v.y; xt[i*4+2]=v.z; xt[i*4+3]=v.w; }
  }
  // preload agg row (80 bf16 = 10 uint4) -> 40 f16 pairs
  half2v a0p[40];
  {
    const uint4* ap = (const uint4*)(aggbuf + ((size_t)(n - n0) * 4 + t) * 80);
#pragma unroll
    for (int q = 0; q < 10; ++q) {
      uint4 v = ap[q];
      unsigned int w[4] = {v.x, v.y, v.z, v.w};
#pragma unroll
      for (int k = 0; k < 4; ++k) {
        unsigned int u = w[k];
        float lo = __uint_as_float(u << 16);
        float hi = __uint_as_float(u & 0xffff0000u);
        a0p[q * 4 + k] = pkrtz(lo, hi);
      }
    }
  }
  float o1[FF];
#pragma unroll
  for (int j = 0; j < FF; ++j) o1[j] = B1[j];
  // xt part, fp32 exact
#pragma unroll
  for (int i = 0; i < FF; ++i) {
    float a = xt[i];
#pragma unroll
    for (int j = 0; j < FF; ++j) o1[j] = fmaf(a, Q1[i * FF + j], o1[j]);
  }
  // a0 view
#pragma unroll 2
  for (int k = 0; k < 40; ++k) {
    half2v act = a0p[k];
    const unsigned int* wr = q1 + k * FF;
#pragma unroll
    for (int j = 0; j < FF; ++j) o1[j] = fdot2(act, u2h2(wr[j]), o1[j]);
  }
  // a1 = a0*c1 view
#pragma unroll 2
  for (int k = 0; k < 40; ++k) {
    half2v act = a0p[k] * c1p;
    const unsigned int* wr = q1 + (40 + k) * FF;
#pragma unroll
    for (int j = 0; j < FF; ++j) o1[j] = fdot2(act, u2h2(wr[j]), o1[j]);
  }
  // a2 = a0*c2 view
#pragma unroll 2
  for (int k = 0; k < 40; ++k) {
    half2v act = a0p[k] * c2p;
    const unsigned int* wr = q1 + (80 + k) * FF;
#pragma unroll
    for (int j = 0; j < FF; ++j) o1[j] = fdot2(act, u2h2(wr[j]), o1[j]);
  }
  // relu + pack, then GEMM2 via dot2
  half2v o1p[10];
#pragma unroll
  for (int i2 = 0; i2 < 10; ++i2)
    o1p[i2] = pkrtz(fmaxf(o1[2*i2], 0.f), fmaxf(o1[2*i2+1], 0.f));
  float o2[FF];
#pragma unroll
  for (int j = 0; j < FF; ++j) o2[j] = B2[j];
#pragma unroll 2
  for (int i2 = 0; i2 < 10; ++i2) {
    half2v act = o1p[i2];
    const unsigned int* wr = q2 + i2 * FF;
#pragma unroll
    for (int j = 0; j < FF; ++j) o2[j] = fdot2(act, u2h2(wr[j]), o2[j]);
  }
  float4* op = (float4*)(out2 + (size_t)n * DD + t * FF);
#pragma unroll
  for (int i = 0; i < 5; ++i) op[i] = make_float4(o2[i*4], o2[i*4+1], o2[i*4+2], o2[i*4+3]);
}

// ---------------- lin layer + BN column partial sums ----------------
__global__ __launch_bounds__(320) void k_lin(const float* __restrict__ out2,
                                             const float* __restrict__ lin_w,
                                             const float* __restrict__ lin_b,
                                             float* __restrict__ outl,
                                             float* __restrict__ colsum, int l) {
  __shared__ float Wl[DD * DD];
  __shared__ float rowbuf[4 * DD];
  __shared__ float red[320];
  int tid = threadIdx.x;
  for (int i = tid; i < DD * DD; i += 320) Wl[i] = lin_w[(size_t)l * DD * DD + i];
  __syncthreads();
  int nl = tid / DD, d = tid - nl * DD;
  float bias = lin_b[l * DD + d];
  float bsum = 0.f, bsq = 0.f;
  for (int base = blockIdx.x * 4; base < NN; base += gridDim.x * 4) {
    int gi = base * DD + tid;
    rowbuf[tid] = (gi < NN * DD) ? out2[gi] : 0.f;
    __syncthreads();
    int n = base + nl;
    if (n < NN) {
      float acc = bias;
#pragma unroll
      for (int i = 0; i < DD; ++i) acc = fmaf(rowbuf[nl * DD + i], Wl[i * DD + d], acc);
      outl[(size_t)n * DD + d] = acc;
      bsum += acc; bsq += acc * acc;
    }
    __syncthreads();
  }
  red[tid] = bsum;
  __syncthreads();
  if (tid < DD) {
    float s = red[tid] + red[tid + DD] + red[tid + 2 * DD] + red[tid + 3 * DD];
    atomicAdd(&colsum[d], s);
  }
  __syncthreads();
  red[tid] = bsq;
  __syncthreads();
  if (tid < DD) {
    float s = red[tid] + red[tid + DD] + red[tid + 2 * DD] + red[tid + 3 * DD];
    atomicAdd(&colsum[DD + d], s);
  }
}

// ---------------- BN finalize ----------------
__global__ __launch_bounds__(128) void k_bnfinal(const float* __restrict__ colsum,
                                                 const float* __restrict__ bn_g,
                                                 const float* __restrict__ bn_b,
                                                 float* __restrict__ bnsc, int l) {
  int d = threadIdx.x;
  if (d >= DD) return;
  float mu = colsum[d] * (1.0f / NN);
  float var = colsum[DD + d] * (1.0f / NN) - mu * mu;
  float sc = bn_g[l * DD + d] * rsqrtf(var + 1e-5f);
  bnsc[d] = sc;
  bnsc[DD + d] = bn_b[l * DD + d] - mu * sc;
}

// ---------------- BN apply + relu + residual into h ----------------
__global__ __launch_bounds__(256) void k_bnapply(const float* __restrict__ outl,
                                                 const float* __restrict__ bnsc,
                                                 float* __restrict__ h) {
  int idx = blockIdx.x * 256 + threadIdx.x;
  if (idx >= NN * DD) return;
  int d = idx % DD;
  float v = fmaf(outl[idx], bnsc[d], bnsc[DD + d]);
  h[idx] += fmaxf(v, 0.f);
}

// ---------------- graph pooling ----------------
__global__ __launch_bounds__(256) void k_gcnt(const int* __restrict__ batch, int* __restrict__ gcnt) {
  __shared__ int hcnt[GG];
  int tid = threadIdx.x;
  if (tid < GG) hcnt[tid] = 0;
  __syncthreads();
  int n = blockIdx.x * 256 + tid;
  if (n < NN) atomicAdd(&hcnt[batch[n]], 1);
  __syncthreads();
  if (tid < GG && hcnt[tid] > 0) atomicAdd(&gcnt[tid], hcnt[tid]);
}

__global__ void k_gstart(const int* __restrict__ gcnt, int* __restrict__ gstart) {
  if (threadIdx.x == 0 && blockIdx.x == 0) {
    int acc = 0;
    for (int g = 0; g < GG; ++g) { gstart[g] = acc; acc += gcnt[g]; }
  }
}

__global__ __launch_bounds__(320) void k_gmean(const float* __restrict__ h,
                                               const int* __restrict__ gstart,
                                               const int* __restrict__ gcnt,
                                               float* __restrict__ gbuf) {
  __shared__ float red[320];
  int g = blockIdx.x, tid = threadIdx.x;
  int nl = tid / DD, d = tid - nl * DD;
  int start = gstart[g], c = gcnt[g];
  float acc = 0.f;
  for (int r = start + nl; r < start + c; r += 4) acc += h[(size_t)r * DD + d];
  red[tid] = acc;
  __syncthreads();
  if (tid < DD) {
    float s = red[tid] + red[tid + DD] + red[tid + 2 * DD] + red[tid + 3 * DD];
    float cf = (c > 0) ? (float)c : 1.0f;
    gbuf[g * DD + tid] = s / cf;
  }
}

// ---------------- final MLP (tiny) ----------------
__global__ __launch_bounds__(64) void k_mlp(const float* __restrict__ gbuf,
                                            const float* __restrict__ w1, const float* __restrict__ b1,
                                            const float* __restrict__ w2, const float* __restrict__ b2,
                                            const float* __restrict__ w3, const float* __restrict__ b3,
                                            float* __restrict__ out) {
  __shared__ float row[DD];
  __shared__ float t1[40];
  __shared__ float t2[20];
  int g = blockIdx.x, tid = threadIdx.x;
  for (int i = tid; i < DD; i += 64) row[i] = gbuf[g * DD + i];
  __syncthreads();
  if (tid < 40) {
    float acc = b1[tid];
#pragma unroll
    for (int i = 0; i < DD; ++i) acc = fmaf(row[i], w1[i * 40 + tid], acc);
    t1[tid] = fmaxf(acc, 0.f);
  }
  __syncthreads();
  if (tid < 20) {
    float acc = b2[tid];
#pragma unroll
    for (int i = 0; i < 40; ++i) acc = fmaf(t1[i], w2[i * 20 + tid], acc);
    t2[tid] = fmaxf(acc, 0.f);
  }
  __syncthreads();
  if (tid == 0) {
    float acc = b3[0];
#pragma unroll
    for (int i = 0; i < 20; ++i) acc = fmaf(t2[i], w3[i], acc);
    out[g] = acc;
  }
}

extern "C" void kernel_launch(void* const* d_in, const int* in_sizes, int n_in,
                              void* d_out, int out_size, void* d_ws, size_t ws_size,
                              hipStream_t stream) {
  const int*   x         = (const int*)d_in[0];
  const int*   ei        = (const int*)d_in[1];
  const int*   batch     = (const int*)d_in[2];
  const float* edge_attr = (const float*)d_in[3];
  const float* atom_emb  = (const float*)d_in[4];
  const float* edge_w    = (const float*)d_in[5];
  const float* edge_b    = (const float*)d_in[6];
  const float* pre_w1    = (const float*)d_in[7];
  const float* pre_b1    = (const float*)d_in[8];
  const float* pre_w2    = (const float*)d_in[9];
  const float* pre_b2    = (const float*)d_in[10];
  const float* post_w1   = (const float*)d_in[11];
  const float* post_b1   = (const float*)d_in[12];
  const float* post_w2   = (const float*)d_in[13];
  const float* post_b2   = (const float*)d_in[14];
  const float* lin_w     = (const float*)d_in[15];
  const float* lin_b     = (const float*)d_in[16];
  const float* bn_g      = (const float*)d_in[17];
  const float* bn_b      = (const float*)d_in[18];
  const float* mlp_w1    = (const float*)d_in[19];
  const float* mlp_b1    = (const float*)d_in[20];
  const float* mlp_w2    = (const float*)d_in[21];
  const float* mlp_b2    = (const float*)d_in[22];
  const float* mlp_w3    = (const float*)d_in[23];
  const float* mlp_b3    = (const float*)d_in[24];
  float* out = (float*)d_out;

  // workspace carve-up — MUST stay within ws_size
  char* ws = (char*)d_ws;
  size_t off = 0;
  auto alloc = [&](size_t bytes) -> void* {
    void* p = ws + off;
    off += (bytes + 15) & ~(size_t)15;
    return p;
  };
  float* h       = (float*)alloc((size_t)NN * DD * 4);           // 16 MB
  float* out2    = (float*)alloc((size_t)NN * DD * 4);           // 16 MB
  unsigned short* predD = (unsigned short*)alloc((size_t)NN * DD * 2); // 8 MB bf16
  unsigned short* predS = (unsigned short*)alloc((size_t)NN * DD * 2); // 8 MB bf16
  int2*  csr2    = (int2*)alloc((size_t)EE * 8);                 // 6.4 MB
  int*   csr_dst = (int*)alloc((size_t)EE * 4);                  // 3.2 MB
  unsigned int* ea16 = (unsigned int*)alloc((size_t)EE * 8 * 4); // 25.6 MB f16 CSR-ordered ea
  int*   row_ptr = (int*)alloc((size_t)(NN + 1) * 4);
  int*   cnt     = (int*)alloc((size_t)NN * 4);
  int*   cursor  = (int*)alloc((size_t)NN * 4);
  float* inv_deg = (float*)alloc((size_t)NN * 4);
  float* s1a     = (float*)alloc((size_t)NN * 4);
  float* s2a     = (float*)alloc((size_t)NN * 4);
  float* colsum  = (float*)alloc(2 * DD * 4);
  float* bnsc    = (float*)alloc(2 * DD * 4);
  float* gbuf    = (float*)alloc((size_t)GG * DD * 4);
  unsigned int* wcpk  = (unsigned int*)alloc((size_t)TT * FF * 8 * 4);
  unsigned int* w2pk  = (unsigned int*)alloc((size_t)TT * FF * 10 * 4);
  unsigned int* q1pk  = (unsigned int*)alloc((size_t)TT * 120 * FF * 4);
  unsigned int* q2pk  = (unsigned int*)alloc((size_t)TT * 10 * FF * 4);
  float* biasc   = (float*)alloc((size_t)TT * FF * 4);
  int*   bsum    = (int*)alloc((size_t)SCAN_B * 4);
  int*   boff    = (int*)alloc((size_t)SCAN_B * 4);
  int*   gcnt    = (int*)alloc((size_t)GG * 4);
  int*   gstart  = (int*)alloc((size_t)(GG + 1) * 4);
  (void)in_sizes; (void)n_in; (void)out_size;

  // remainder -> aggbuf (bf16 stats) + f16 m chunk buffer; outl aliases region.
  size_t rest = (ws_size > off) ? (ws_size - off) : 0;
  static const int cands[] = {1, 2, 4, 5, 8, 10, 20, 25, 40, 50};
  int c = -1, capSlots = 0, nodesPer = 0;
  size_t aggBytes = 0;
  for (int ci = 0; ci < 10; ++ci) {
    int cc = cands[ci];
    int np = (NN + cc - 1) / cc;
    size_t ab = ((size_t)np * 4 * 80 * 2 + 63) & ~(size_t)63;    // bf16 stats
    int slots = EE / cc + 25000; if (slots > EE) slots = EE;
    slots = (slots + 63) & ~63;
    size_t mb = (size_t)slots * DD * 2;                          // f16: 40 dword rows
    if (ab + mb <= rest && ab + mb >= (size_t)NN * DD * 4) {     // outl (16 MB) must fit alias
      c = cc; capSlots = slots; nodesPer = np; aggBytes = ab;
      break;
    }
  }
  if (c < 0) { // degenerate fallback
    c = 50; nodesPer = (NN + c - 1) / c;
    aggBytes = ((size_t)nodesPer * 4 * 80 * 2 + 63) & ~(size_t)63;
    size_t mb = (rest > aggBytes) ? rest - aggBytes : 0;
    capSlots = (int)(mb / (DD * 2)) & ~63;
  }
  unsigned short* aggbuf = (unsigned short*)(ws + off);
  unsigned int* mbuf = (unsigned int*)(ws + off + aggBytes);
  float* outl = (float*)(ws + off); // alias: k_lin runs after all chunks of the layer

  hipMemsetAsync(cnt, 0, (size_t)NN * 4, stream);
  k_h<<<(NN * DD + 255) / 256, 256, 0, stream>>>(x, atom_emb, h);
  k_deg<<<(EE + 255) / 256, 256, 0, stream>>>(ei, cnt);
  k_scan_sum<<<SCAN_B, 1024, 0, stream>>>(cnt, bsum);
  k_scan_top<<<1, 64, 0, stream>>>(bsum, boff, row_ptr);
  k_scan_apply<<<SCAN_B, 1024, 0, stream>>>(cnt, boff, row_ptr, cursor);
  k_csrfill<<<(EE + 255) / 256, 256, 0, stream>>>(ei, cursor, csr2, csr_dst);
  k_eagather<<<(EE + 255) / 256, 256, 0, stream>>>(csr2, edge_attr, ea16);
  k_nodeparams<<<(NN + 255) / 256, 256, 0, stream>>>(cnt, inv_deg, s1a, s2a);

  for (int l = 0; l < LL; ++l) {
    k_wcomb<<<TT, 64, 0, stream>>>(edge_w, edge_b, pre_w1, pre_b1, pre_w2, wcpk, w2pk, biasc, l);
    k_postpk<<<TT, 64, 0, stream>>>(post_w1, post_w2, q1pk, q2pk, l);
    k_prenode<<<(NN + 63) / 64, 256, 0, stream>>>(h, pre_w1, biasc, predD, predS, l);
    for (int ck = 0; ck < c; ++ck) {
      int n0 = ck * nodesPer;
      int n1 = n0 + nodesPer; if (n1 > NN) n1 = NN;
      if (n0 >= n1) continue;
      int preBlocks = (capSlots + 63) / 64;
      k_pre<<<preBlocks, 256, 0, stream>>>(predD, predS, ea16, csr2, csr_dst, row_ptr,
          wcpk, w2pk, pre_b2, mbuf, l, n0, n1, capSlots);
      int aggBlocks = ((n1 - n0 + 31) / 32) * 4;
      k_agg<<<aggBlocks, 320, 0, stream>>>(mbuf, row_ptr, inv_deg, aggbuf, n0, n1, capSlots);
      int tiles = (n1 - n0 + 255) / 256;
      k_post2<<<tiles * TT, 256, 0, stream>>>(h, aggbuf, s1a, s2a,
          post_w1, post_b1, q1pk, q2pk, post_b2, out2, l, n0, n1, tiles);
    }
    hipMemsetAsync(colsum, 0, 2 * DD * 4, stream);
    k_lin<<<512, 320, 0, stream>>>(out2, lin_w, lin_b, outl, colsum, l);
    k_bnfinal<<<1, 128, 0, stream>>>(colsum, bn_g, bn_b, bnsc, l);
    k_bnapply<<<(NN * DD + 255) / 256, 256, 0, stream>>>(outl, bnsc, h);
  }

  hipMemsetAsync(gcnt, 0, (size_t)GG * 4, stream);
  k_gcnt<<<(NN + 255) / 256, 256, 0, stream>>>(batch, gcnt);
  k_gstart<<<1, 64, 0, stream>>>(gcnt, gstart);
  k_gmean<<<GG, 320, 0, stream>>>(h, gstart, gcnt, gbuf);
  k_mlp<<<GG, 64, 0, stream>>>(gbuf, mlp_w1, mlp_b1, mlp_w2, mlp_b2, mlp_w3, mlp_b3, out);
}

// Round 6
// 1452.154 us; speedup vs baseline: 1.0991x; 1.0276x over previous
//
#include <hip/hip_runtime.h>
#include <hip/hip_bf16.h>

// Problem constants (from reference)
#define NN 50000
#define EE 800000
#define GG 128
#define LL 4
#define TT 4
#define FF 20
#define DD 80
#define SCAN_B ((NN + 1023) / 1024)   // 49
#define TILE_N 32                     // nodes per k_preagg block (avg 512 slots)
static constexpr float AVG_LOG = 2.8332133440562162f; // ln(17)

typedef __fp16 half2v __attribute__((ext_vector_type(2)));

__device__ __forceinline__ float bf2f(unsigned short u) {
  return __uint_as_float((unsigned)u << 16);
}
__device__ __forceinline__ unsigned short f2bf(float f) {
  __hip_bfloat16 b = __float2bfloat16(f); // RNE
  return *(unsigned short*)&b;
}
__device__ __forceinline__ half2v pkrtz(float a, float b) {
#if __has_builtin(__builtin_amdgcn_cvt_pkrtz)
  return __builtin_amdgcn_cvt_pkrtz(a, b);
#else
  half2v h; h.x = (__fp16)a; h.y = (__fp16)b; return h;
#endif
}
__device__ __forceinline__ float fdot2(half2v a, half2v b, float c) {
#if __has_builtin(__builtin_amdgcn_fdot2)
  return __builtin_amdgcn_fdot2(a, b, c, false);
#else
  return fmaf((float)a.x, (float)b.x, fmaf((float)a.y, (float)b.y, c));
#endif
}
__device__ __forceinline__ half2v u2h2(unsigned int u) {
  return __builtin_bit_cast(half2v, u);
}
__device__ __forceinline__ unsigned int h22u(half2v h) {
  return __builtin_bit_cast(unsigned int, h);
}
__device__ __forceinline__ unsigned int packh2_rne(float a, float b) {
  half2v h; h.x = (__fp16)a; h.y = (__fp16)b; // RNE casts for weights
  return h22u(h);
}
__device__ __forceinline__ unsigned int pack_bf16(float a, float b) {
  return (unsigned int)f2bf(a) | ((unsigned int)f2bf(b) << 16);
}

// ---------------- h init: h[n,d] = sum_i atom_emb[i, x[n,i], d] ----------------
__global__ __launch_bounds__(256) void k_h(const int* __restrict__ x,
                                           const float* __restrict__ atom_emb,
                                           float* __restrict__ h) {
  int idx = blockIdx.x * 256 + threadIdx.x;
  if (idx >= NN * DD) return;
  int n = idx / DD, d = idx - n * DD;
  const int* xr = x + n * 9;
  float acc = 0.f;
#pragma unroll
  for (int i = 0; i < 9; ++i) {
    int v = xr[i];
    acc += atom_emb[(i * 16 + v) * DD + d];
  }
  h[idx] = acc;
}

// ---------------- degree count ----------------
__global__ __launch_bounds__(256) void k_deg(const int* __restrict__ ei, int* __restrict__ cnt) {
  int e = blockIdx.x * 256 + threadIdx.x;
  if (e >= EE) return;
  atomicAdd(&cnt[ei[EE + e]], 1); // dst = edge_index[1][e]
}

// ---------------- hierarchical exclusive scan ----------------
__global__ __launch_bounds__(1024) void k_scan_sum(const int* __restrict__ cnt, int* __restrict__ bsum) {
  __shared__ int red[1024];
  int tid = threadIdx.x;
  int i = blockIdx.x * 1024 + tid;
  red[tid] = (i < NN) ? cnt[i] : 0;
  __syncthreads();
  for (int off = 512; off > 0; off >>= 1) {
    if (tid < off) red[tid] += red[tid + off];
    __syncthreads();
  }
  if (tid == 0) bsum[blockIdx.x] = red[0];
}

__global__ void k_scan_top(const int* __restrict__ bsum, int* __restrict__ boff,
                           int* __restrict__ row_ptr) {
  if (threadIdx.x == 0 && blockIdx.x == 0) {
    int acc = 0;
    for (int b = 0; b < SCAN_B; ++b) { boff[b] = acc; acc += bsum[b]; }
    row_ptr[NN] = acc;
  }
}

__global__ __launch_bounds__(1024) void k_scan_apply(const int* __restrict__ cnt,
                                                     const int* __restrict__ boff,
                                                     int* __restrict__ row_ptr,
                                                     int* __restrict__ cursor) {
  __shared__ int sm[1024];
  int tid = threadIdx.x;
  int i = blockIdx.x * 1024 + tid;
  int v = (i < NN) ? cnt[i] : 0;
  sm[tid] = v;
  __syncthreads();
  for (int off = 1; off < 1024; off <<= 1) {
    int t = (tid >= off) ? sm[tid - off] : 0;
    __syncthreads();
    sm[tid] += t;
    __syncthreads();
  }
  int excl = boff[blockIdx.x] + sm[tid] - v;
  if (i < NN) { row_ptr[i] = excl; cursor[i] = excl; }
}

// ---------------- CSR fill: slot -> src / eid / dst (split arrays) ----------------
__global__ __launch_bounds__(256) void k_csrfill(const int* __restrict__ ei,
                                                 int* __restrict__ cursor,
                                                 int* __restrict__ csr_src,
                                                 int* __restrict__ csr_eid,
                                                 int* __restrict__ csr_dst) {
  int e = blockIdx.x * 256 + threadIdx.x;
  if (e >= EE) return;
  int dst = ei[EE + e];
  int slot = atomicAdd(&cursor[dst], 1);
  csr_src[slot] = ei[e];
  csr_eid[slot] = e;
  csr_dst[slot] = dst;
}

// ---------------- one-time edge_attr gather into CSR slot order, f16 pairs ----------------
__global__ __launch_bounds__(256) void k_eagather(const int* __restrict__ csr_eid,
                                                  const float* __restrict__ edge_attr,
                                                  unsigned int* __restrict__ ea16) {
  int sl = blockIdx.x * 256 + threadIdx.x;
  if (sl >= EE) return;
  int e = csr_eid[sl];
  const float4* ap = (const float4*)(edge_attr + (size_t)e * 16);
  uint4 o0, o1;
  float4 v0 = ap[0], v1 = ap[1], v2 = ap[2], v3 = ap[3];
  o0.x = packh2_rne(v0.x, v0.y); o0.y = packh2_rne(v0.z, v0.w);
  o0.z = packh2_rne(v1.x, v1.y); o0.w = packh2_rne(v1.z, v1.w);
  o1.x = packh2_rne(v2.x, v2.y); o1.y = packh2_rne(v2.z, v2.w);
  o1.z = packh2_rne(v3.x, v3.y); o1.w = packh2_rne(v3.z, v3.w);
  uint4* op = (uint4*)(ea16 + (size_t)sl * 8);
  op[0] = o0; op[1] = o1;
}

// ---------------- per-node params ----------------
__global__ __launch_bounds__(256) void k_nodeparams(const int* __restrict__ cnt,
                                                    float* __restrict__ inv_deg,
                                                    float* __restrict__ s1a,
                                                    float* __restrict__ s2a) {
  int n = blockIdx.x * 256 + threadIdx.x;
  if (n >= NN) return;
  int c = cnt[n];
  float deg = (c > 0) ? (float)c : 1.0f;
  inv_deg[n] = 1.0f / deg;
  float logd = logf(deg + 1.0f);
  s1a[n] = logd / AVG_LOG;
  s2a[n] = AVG_LOG / logd;
}

// ---------------- per-layer weight composition + f16 pair packing ----------------
__global__ __launch_bounds__(64) void k_wcomb(const float* __restrict__ edge_w,
                                              const float* __restrict__ edge_b,
                                              const float* __restrict__ pre_w1,
                                              const float* __restrict__ pre_b1,
                                              const float* __restrict__ pre_w2,
                                              unsigned int* __restrict__ wcpk,
                                              unsigned int* __restrict__ w2pk,
                                              float* __restrict__ biasc, int l) {
  int t = blockIdx.x;
  int wt = l * TT + t;
  const float* W1 = pre_w1 + (size_t)wt * 1200; // [60][20]
  const float* W2 = pre_w2 + (size_t)wt * 400;  // [20][20]
  const float* ew = edge_w + (size_t)l * 16 * FF;
  const float* eb = edge_b + (size_t)l * FF;
  int j = threadIdx.x;
  if (j >= FF) return;
  float col[16];
  for (int i = 0; i < 16; ++i) {
    float acc = 0.f;
#pragma unroll
    for (int f = 0; f < FF; ++f) acc = fmaf(ew[i * FF + f], W1[(40 + f) * FF + j], acc);
    col[i] = acc;
  }
#pragma unroll
  for (int i2 = 0; i2 < 8; ++i2)
    wcpk[((size_t)t * FF + j) * 8 + i2] = packh2_rne(col[2 * i2], col[2 * i2 + 1]);
#pragma unroll
  for (int i2 = 0; i2 < 10; ++i2)
    w2pk[((size_t)t * FF + j) * 10 + i2] = packh2_rne(W2[(2 * i2) * FF + j], W2[(2 * i2 + 1) * FF + j]);
  float b = pre_b1[wt * FF + j];
#pragma unroll
  for (int f = 0; f < FF; ++f) b = fmaf(eb[f], W1[(40 + f) * FF + j], b);
  biasc[t * FF + j] = b;
}

// ---------------- post-MLP weight packing: Q1 rows [20,260) + Q2 as f16 pairs ----------------
__global__ __launch_bounds__(64) void k_postpk(const float* __restrict__ post_w1,
                                               const float* __restrict__ post_w2,
                                               unsigned int* __restrict__ q1pk,
                                               unsigned int* __restrict__ q2pk, int l) {
  int t = blockIdx.x;
  int wt = l * TT + t;
  const float* Q1 = post_w1 + (size_t)wt * 5200;
  const float* Q2 = post_w2 + (size_t)wt * 400;
  int j = threadIdx.x;
  if (j >= FF) return;
  for (int i2 = 0; i2 < 120; ++i2) {
    int blk = i2 / 40, k = i2 - blk * 40;
    int r0 = 20 + 80 * blk + 2 * k;
    q1pk[((size_t)t * 120 + i2) * FF + j] = packh2_rne(Q1[r0 * FF + j], Q1[(r0 + 1) * FF + j]);
  }
#pragma unroll
  for (int i2 = 0; i2 < 10; ++i2)
    q2pk[((size_t)t * 10 + i2) * FF + j] = packh2_rne(Q2[(2 * i2) * FF + j], Q2[(2 * i2 + 1) * FF + j]);
}

// ---------------- per-node pre contributions (bf16 out) ----------------
__global__ __launch_bounds__(256) void k_prenode(
    const float* __restrict__ h, const float* __restrict__ pre_w1,
    const float* __restrict__ biasc,
    unsigned short* __restrict__ predD, unsigned short* __restrict__ predS, int l) {
  int tid = threadIdx.x;
  int t = tid >> 6, lane = tid & 63;
  int n = blockIdx.x * 64 + lane;
  if (n >= NN) return;
  int wt_u = __builtin_amdgcn_readfirstlane(l * TT + t);
  const float* W1 = pre_w1 + (size_t)wt_u * 1200;
  const float* bc = biasc + t * FF;
  float xt[FF];
  {
    const float4* pp = (const float4*)(h + (size_t)n * DD + t * FF);
#pragma unroll
    for (int i = 0; i < 5; ++i) { float4 v = pp[i]; xt[i*4]=v.x; xt[i*4+1]=v.y; xt[i*4+2]=v.z; xt[i*4+3]=v.w; }
  }
  float d[FF], s[FF];
#pragma unroll
  for (int j = 0; j < FF; ++j) { d[j] = bc[j]; s[j] = 0.f; }
#pragma unroll
  for (int i = 0; i < FF; ++i) {
    float a = xt[i];
#pragma unroll
    for (int j = 0; j < FF; ++j) {
      d[j] = fmaf(a, W1[i * FF + j], d[j]);
      s[j] = fmaf(a, W1[(FF + i) * FF + j], s[j]);
    }
  }
  ushort4* pd = (ushort4*)(predD + (size_t)n * DD + t * FF);
  ushort4* ps = (ushort4*)(predS + (size_t)n * DD + t * FF);
#pragma unroll
  for (int i = 0; i < 5; ++i) {
    pd[i] = make_ushort4(f2bf(d[i*4]), f2bf(d[i*4+1]), f2bf(d[i*4+2]), f2bf(d[i*4+3]));
    ps[i] = make_ushort4(f2bf(s[i*4]), f2bf(s[i*4+1]), f2bf(s[i*4+2]), f2bf(s[i*4+3]));
  }
}

// ---------------- FUSED edge pre-MLP + aggregation ----------------
// Grid = tiles*TT (tower-major). Block = 256 threads, one tower, 32-node CSR tile.
// Window loop: compute phase (1 edge/thread -> m2[20] -> LDS, stride-11 pad),
// reduce phase (thread owns (node, ch-pair) items; register stats). m never
// touches HBM (-250 MB/layer vs k_pre+k_agg).
__global__ __launch_bounds__(256) void k_preagg(
    const unsigned short* __restrict__ predD,
    const unsigned short* __restrict__ predS,
    const unsigned int* __restrict__ ea16,
    const int* __restrict__ csr_src,
    const int* __restrict__ csr_dst,
    const int* __restrict__ row_ptr,
    const float* __restrict__ inv_deg,
    const unsigned int* __restrict__ wcpk,
    const unsigned int* __restrict__ w2pk,
    const float* __restrict__ pre_b2,
    unsigned short* __restrict__ aggbuf,
    int l, int tiles) {
  __shared__ int nbr[TILE_N + 1];
  __shared__ float dDs[TILE_N * FF];
  __shared__ unsigned int m2w[256 * 11];   // stride-11 pad: conflict-free
  int tid = threadIdx.x;
  int t = blockIdx.x / tiles;              // block-uniform tower
  int tile = blockIdx.x - t * tiles;
  int n0 = tile * TILE_N;
  const unsigned int* Wcp = wcpk + (size_t)t * FF * 8;
  const unsigned int* W2p = w2pk + (size_t)t * FF * 10;
  const float* b2 = pre_b2 + (size_t)(l * TT + t) * FF;

  if (tid <= TILE_N) {
    int node = n0 + tid; if (node > NN) node = NN;
    nbr[tid] = row_ptr[node];
  }
  for (int i = tid; i < TILE_N * FF; i += 256) {
    int ni = i / FF, ch = i - ni * FF;
    int node = n0 + ni;
    dDs[i] = (node < NN) ? bf2f(predD[(size_t)node * DD + t * FF + ch]) : 0.f;
  }
  __syncthreads();
  int tbeg = nbr[0], tend = nbr[TILE_N];

  // reduce items: item0 = tid (always), item1 = 256+tid (tid<64)
  int ni0 = tid / 10, pr0 = tid - ni0 * 10;
  int it1 = 256 + tid;
  int ni1 = it1 / 10, pr1 = it1 - ni1 * 10;
  bool has1 = (tid < TILE_N * 10 - 256);   // 64 threads
  int begA = nbr[ni0], endA = nbr[ni0 + 1];
  int begB = has1 ? nbr[ni1] : 0, endB = has1 ? nbr[ni1 + 1] : 0;
  float a_s0=0.f,a_s1=0.f,a_q0=0.f,a_q1=0.f,a_n0=3.4e38f,a_n1=3.4e38f,a_x0=-3.4e38f,a_x1=-3.4e38f;
  float b_s0=0.f,b_s1=0.f,b_q0=0.f,b_q1=0.f,b_n0=3.4e38f,b_n1=3.4e38f,b_x0=-3.4e38f,b_x1=-3.4e38f;

  for (int wb = tbeg; wb < tend; wb += 256) {
    int p = wb + tid;
    if (p < tend) {
      int src = csr_src[p];
      int ni = csr_dst[p] - n0;
      float m1[FF];
      {
        const float4* dd = (const float4*)(dDs + ni * FF);
        const ushort4* qq = (const ushort4*)(predS + (size_t)src * DD + t * FF);
#pragma unroll
        for (int i = 0; i < 5; ++i) {
          float4 d4 = dd[i];
          ushort4 v = qq[i];
          m1[i*4+0] = d4.x + bf2f(v.x);
          m1[i*4+1] = d4.y + bf2f(v.y);
          m1[i*4+2] = d4.z + bf2f(v.z);
          m1[i*4+3] = d4.w + bf2f(v.w);
        }
      }
      half2v eap[8];
      {
        const uint4* ep = (const uint4*)(ea16 + (size_t)p * 8);
        uint4 e0 = ep[0], e1 = ep[1];
        eap[0] = u2h2(e0.x); eap[1] = u2h2(e0.y); eap[2] = u2h2(e0.z); eap[3] = u2h2(e0.w);
        eap[4] = u2h2(e1.x); eap[5] = u2h2(e1.y); eap[6] = u2h2(e1.z); eap[7] = u2h2(e1.w);
      }
#pragma unroll
      for (int j = 0; j < FF; ++j) {
        float c = m1[j];
#pragma unroll
        for (int i2 = 0; i2 < 8; ++i2) c = fdot2(eap[i2], u2h2(Wcp[j * 8 + i2]), c);
        m1[j] = c;
      }
      half2v mp[10];
#pragma unroll
      for (int pr = 0; pr < 10; ++pr)
        mp[pr] = pkrtz(fmaxf(m1[2*pr], 0.f), fmaxf(m1[2*pr+1], 0.f));
      float m2[FF];
#pragma unroll
      for (int j = 0; j < FF; ++j) {
        float c = b2[j];
#pragma unroll
        for (int i2 = 0; i2 < 10; ++i2) c = fdot2(mp[i2], u2h2(W2p[j * 10 + i2]), c);
        m2[j] = c;
      }
      unsigned int* row = m2w + tid * 11;
#pragma unroll
      for (int pr = 0; pr < 10; ++pr) row[pr] = h22u(pkrtz(m2[2*pr], m2[2*pr+1]));
    }
    __syncthreads();
    int we = (wb + 256 < tend) ? (wb + 256) : tend;
    {
      int lo = begA > wb ? begA : wb;
      int hi = endA < we ? endA : we;
      for (int s = lo; s < hi; ++s) {
        half2v h2 = u2h2(m2w[(s - wb) * 11 + pr0]);
        float v0 = (float)h2.x, v1 = (float)h2.y;
        a_s0 += v0; a_q0 = fmaf(v0, v0, a_q0); a_n0 = fminf(a_n0, v0); a_x0 = fmaxf(a_x0, v0);
        a_s1 += v1; a_q1 = fmaf(v1, v1, a_q1); a_n1 = fminf(a_n1, v1); a_x1 = fmaxf(a_x1, v1);
      }
    }
    if (has1) {
      int lo = begB > wb ? begB : wb;
      int hi = endB < we ? endB : we;
      for (int s = lo; s < hi; ++s) {
        half2v h2 = u2h2(m2w[(s - wb) * 11 + pr1]);
        float v0 = (float)h2.x, v1 = (float)h2.y;
        b_s0 += v0; b_q0 = fmaf(v0, v0, b_q0); b_n0 = fminf(b_n0, v0); b_x0 = fmaxf(b_x0, v0);
        b_s1 += v1; b_q1 = fmaf(v1, v1, b_q1); b_n1 = fminf(b_n1, v1); b_x1 = fmaxf(b_x1, v1);
      }
    }
    __syncthreads();
  }

  // finalize item0
  {
    int n = n0 + ni0;
    if (n < NN) {
      float inv = inv_deg[n];
      float mu0 = a_s0 * inv, mu1 = a_s1 * inv;
      float sd0 = sqrtf(fmaxf(a_q0 * inv - mu0 * mu0, 0.f) + 1e-5f);
      float sd1 = sqrtf(fmaxf(a_q1 * inv - mu1 * mu1, 0.f) + 1e-5f);
      float mn0 = a_n0, mn1 = a_n1, mx0 = a_x0, mx1 = a_x1;
      if (endA <= begA) { mn0 = 0.f; mn1 = 0.f; mx0 = 0.f; mx1 = 0.f; }
      unsigned short* ab = aggbuf + ((size_t)n * 4 + t) * 80;
      ((unsigned int*)(ab))[pr0]      = pack_bf16(mu0, mu1);
      ((unsigned int*)(ab + 20))[pr0] = pack_bf16(mn0, mn1);
      ((unsigned int*)(ab + 40))[pr0] = pack_bf16(mx0, mx1);
      ((unsigned int*)(ab + 60))[pr0] = pack_bf16(sd0, sd1);
    }
  }
  if (has1) {
    int n = n0 + ni1;
    if (n < NN) {
      float inv = inv_deg[n];
      float mu0 = b_s0 * inv, mu1 = b_s1 * inv;
      float sd0 = sqrtf(fmaxf(b_q0 * inv - mu0 * mu0, 0.f) + 1e-5f);
      float sd1 = sqrtf(fmaxf(b_q1 * inv - mu1 * mu1, 0.f) + 1e-5f);
      float mn0 = b_n0, mn1 = b_n1, mx0 = b_x0, mx1 = b_x1;
      if (endB <= begB) { mn0 = 0.f; mn1 = 0.f; mx0 = 0.f; mx1 = 0.f; }
      unsigned short* ab = aggbuf + ((size_t)n * 4 + t) * 80;
      ((unsigned int*)(ab))[pr1]      = pack_bf16(mu0, mu1);
      ((unsigned int*)(ab + 20))[pr1] = pack_bf16(mn0, mn1);
      ((unsigned int*)(ab + 40))[pr1] = pack_bf16(mx0, mx1);
      ((unsigned int*)(ab + 60))[pr1] = pack_bf16(sd0, sd1);
    }
  }
}

// ---------------- node-parallel post-MLP via dot2, register-preloaded activations ----------------
__global__ __launch_bounds__(256) void k_post2(
    const float* __restrict__ h, const unsigned short* __restrict__ aggbuf,
    const float* __restrict__ s1a, const float* __restrict__ s2a,
    const float* __restrict__ post_w1, const float* __restrict__ post_b1,
    const unsigned int* __restrict__ q1pk, const unsigned int* __restrict__ q2pk,
    const float* __restrict__ post_b2,
    float* __restrict__ out2, int l, int tiles) {
  int t = blockIdx.x / tiles;          // block-uniform tower
  int tile = blockIdx.x - t * tiles;
  int wt_u = l * TT + t;
  const float* Q1 = post_w1 + (size_t)wt_u * 5200;  // fp32 rows [0,20) for xt part
  const float* B1 = post_b1 + (size_t)wt_u * FF;
  const float* B2 = post_b2 + (size_t)wt_u * FF;
  const unsigned int* q1 = q1pk + (size_t)t * 120 * FF;
  const unsigned int* q2 = q2pk + (size_t)t * 10 * FF;
  int n = tile * 256 + threadIdx.x;
  if (n >= NN) return;
  float c1 = s1a[n], c2 = s2a[n];
  half2v c1p = pkrtz(c1, c1), c2p = pkrtz(c2, c2);
  float xt[FF];
  {
    const float4* pp = (const float4*)(h + (size_t)n * DD + t * FF);
#pragma unroll
    for (int i = 0; i < 5; ++i) { float4 v = pp[i]; xt[i*4]=v.x; xt[i*4+1]=v.y; xt[i*4+2]=v.z; xt[i*4+3]=v.w; }
  }
  half2v a0p[40];
  {
    const uint4* ap = (const uint4*)(aggbuf + ((size_t)n * 4 + t) * 80);
#pragma unroll
    for (int q = 0; q < 10; ++q) {
      uint4 v = ap[q];
      unsigned int w[4] = {v.x, v.y, v.z, v.w};
#pragma unroll
      for (int k = 0; k < 4; ++k) {
        unsigned int u = w[k];
        float lo = __uint_as_float(u << 16);
        float hi = __uint_as_float(u & 0xffff0000u);
        a0p[q * 4 + k] = pkrtz(lo, hi);
      }
    }
  }
  float o1[FF];
#pragma unroll
  for (int j = 0; j < FF; ++j) o1[j] = B1[j];
#pragma unroll
  for (int i = 0; i < FF; ++i) {
    float a = xt[i];
#pragma unroll
    for (int j = 0; j < FF; ++j) o1[j] = fmaf(a, Q1[i * FF + j], o1[j]);
  }
#pragma unroll 2
  for (int k = 0; k < 40; ++k) {
    half2v act = a0p[k];
    const unsigned int* wr = q1 + k * FF;
#pragma unroll
    for (int j = 0; j < FF; ++j) o1[j] = fdot2(act, u2h2(wr[j]), o1[j]);
  }
#pragma unroll 2
  for (int k = 0; k < 40; ++k) {
    half2v act = a0p[k] * c1p;
    const unsigned int* wr = q1 + (40 + k) * FF;
#pragma unroll
    for (int j = 0; j < FF; ++j) o1[j] = fdot2(act, u2h2(wr[j]), o1[j]);
  }
#pragma unroll 2
  for (int k = 0; k < 40; ++k) {
    half2v act = a0p[k] * c2p;
    const unsigned int* wr = q1 + (80 + k) * FF;
#pragma unroll
    for (int j = 0; j < FF; ++j) o1[j] = fdot2(act, u2h2(wr[j]), o1[j]);
  }
  half2v o1p[10];
#pragma unroll
  for (int i2 = 0; i2 < 10; ++i2)
    o1p[i2] = pkrtz(fmaxf(o1[2*i2], 0.f), fmaxf(o1[2*i2+1], 0.f));
  float o2[FF];
#pragma unroll
  for (int j = 0; j < FF; ++j) o2[j] = B2[j];
#pragma unroll 2
  for (int i2 = 0; i2 < 10; ++i2) {
    half2v act = o1p[i2];
    const unsigned int* wr = q2 + i2 * FF;
#pragma unroll
    for (int j = 0; j < FF; ++j) o2[j] = fdot2(act, u2h2(wr[j]), o2[j]);
  }
  float4* op = (float4*)(out2 + (size_t)n * DD + t * FF);
#pragma unroll
  for (int i = 0; i < 5; ++i) op[i] = make_float4(o2[i*4], o2[i*4+1], o2[i*4+2], o2[i*4+3]);
}

// ---------------- lin layer + BN column partial sums ----------------
__global__ __launch_bounds__(320) void k_lin(const float* __restrict__ out2,
                                             const float* __restrict__ lin_w,
                                             const float* __restrict__ lin_b,
                                             float* __restrict__ outl,
                                             float* __restrict__ colsum, int l) {
  __shared__ float Wl[DD * DD];
  __shared__ float rowbuf[4 * DD];
  __shared__ float red[320];
  int tid = threadIdx.x;
  for (int i = tid; i < DD * DD; i += 320) Wl[i] = lin_w[(size_t)l * DD * DD + i];
  __syncthreads();
  int nl = tid / DD, d = tid - nl * DD;
  float bias = lin_b[l * DD + d];
  float bsum = 0.f, bsq = 0.f;
  for (int base = blockIdx.x * 4; base < NN; base += gridDim.x * 4) {
    int gi = base * DD + tid;
    rowbuf[tid] = (gi < NN * DD) ? out2[gi] : 0.f;
    __syncthreads();
    int n = base + nl;
    if (n < NN) {
      float acc = bias;
#pragma unroll
      for (int i = 0; i < DD; ++i) acc = fmaf(rowbuf[nl * DD + i], Wl[i * DD + d], acc);
      outl[(size_t)n * DD + d] = acc;
      bsum += acc; bsq += acc * acc;
    }
    __syncthreads();
  }
  red[tid] = bsum;
  __syncthreads();
  if (tid < DD) {
    float s = red[tid] + red[tid + DD] + red[tid + 2 * DD] + red[tid + 3 * DD];
    atomicAdd(&colsum[d], s);
  }
  __syncthreads();
  red[tid] = bsq;
  __syncthreads();
  if (tid < DD) {
    float s = red[tid] + red[tid + DD] + red[tid + 2 * DD] + red[tid + 3 * DD];
    atomicAdd(&colsum[DD + d], s);
  }
}

// ---------------- BN finalize ----------------
__global__ __launch_bounds__(128) void k_bnfinal(const float* __restrict__ colsum,
                                                 const float* __restrict__ bn_g,
                                                 const float* __restrict__ bn_b,
                                                 float* __restrict__ bnsc, int l) {
  int d = threadIdx.x;
  if (d >= DD) return;
  float mu = colsum[d] * (1.0f / NN);
  float var = colsum[DD + d] * (1.0f / NN) - mu * mu;
  float sc = bn_g[l * DD + d] * rsqrtf(var + 1e-5f);
  bnsc[d] = sc;
  bnsc[DD + d] = bn_b[l * DD + d] - mu * sc;
}

// ---------------- BN apply + relu + residual into h ----------------
__global__ __launch_bounds__(256) void k_bnapply(const float* __restrict__ outl,
                                                 const float* __restrict__ bnsc,
                                                 float* __restrict__ h) {
  int idx = blockIdx.x * 256 + threadIdx.x;
  if (idx >= NN * DD) return;
  int d = idx % DD;
  float v = fmaf(outl[idx], bnsc[d], bnsc[DD + d]);
  h[idx] += fmaxf(v, 0.f);
}

// ---------------- graph pooling ----------------
__global__ __launch_bounds__(256) void k_gcnt(const int* __restrict__ batch, int* __restrict__ gcnt) {
  __shared__ int hcnt[GG];
  int tid = threadIdx.x;
  if (tid < GG) hcnt[tid] = 0;
  __syncthreads();
  int n = blockIdx.x * 256 + tid;
  if (n < NN) atomicAdd(&hcnt[batch[n]], 1);
  __syncthreads();
  if (tid < GG && hcnt[tid] > 0) atomicAdd(&gcnt[tid], hcnt[tid]);
}

__global__ void k_gstart(const int* __restrict__ gcnt, int* __restrict__ gstart) {
  if (threadIdx.x == 0 && blockIdx.x == 0) {
    int acc = 0;
    for (int g = 0; g < GG; ++g) { gstart[g] = acc; acc += gcnt[g]; }
  }
}

__global__ __launch_bounds__(320) void k_gmean(const float* __restrict__ h,
                                               const int* __restrict__ gstart,
                                               const int* __restrict__ gcnt,
                                               float* __restrict__ gbuf) {
  __shared__ float red[320];
  int g = blockIdx.x, tid = threadIdx.x;
  int nl = tid / DD, d = tid - nl * DD;
  int start = gstart[g], c = gcnt[g];
  float acc = 0.f;
  for (int r = start + nl; r < start + c; r += 4) acc += h[(size_t)r * DD + d];
  red[tid] = acc;
  __syncthreads();
  if (tid < DD) {
    float s = red[tid] + red[tid + DD] + red[tid + 2 * DD] + red[tid + 3 * DD];
    float cf = (c > 0) ? (float)c : 1.0f;
    gbuf[g * DD + tid] = s / cf;
  }
}

// ---------------- final MLP (tiny) ----------------
__global__ __launch_bounds__(64) void k_mlp(const float* __restrict__ gbuf,
                                            const float* __restrict__ w1, const float* __restrict__ b1,
                                            const float* __restrict__ w2, const float* __restrict__ b2,
                                            const float* __restrict__ w3, const float* __restrict__ b3,
                                            float* __restrict__ out) {
  __shared__ float row[DD];
  __shared__ float t1[40];
  __shared__ float t2[20];
  int g = blockIdx.x, tid = threadIdx.x;
  for (int i = tid; i < DD; i += 64) row[i] = gbuf[g * DD + i];
  __syncthreads();
  if (tid < 40) {
    float acc = b1[tid];
#pragma unroll
    for (int i = 0; i < DD; ++i) acc = fmaf(row[i], w1[i * 40 + tid], acc);
    t1[tid] = fmaxf(acc, 0.f);
  }
  __syncthreads();
  if (tid < 20) {
    float acc = b2[tid];
#pragma unroll
    for (int i = 0; i < 40; ++i) acc = fmaf(t1[i], w2[i * 20 + tid], acc);
    t2[tid] = fmaxf(acc, 0.f);
  }
  __syncthreads();
  if (tid == 0) {
    float acc = b3[0];
#pragma unroll
    for (int i = 0; i < 20; ++i) acc = fmaf(t2[i], w3[i], acc);
    out[g] = acc;
  }
}

extern "C" void kernel_launch(void* const* d_in, const int* in_sizes, int n_in,
                              void* d_out, int out_size, void* d_ws, size_t ws_size,
                              hipStream_t stream) {
  const int*   x         = (const int*)d_in[0];
  const int*   ei        = (const int*)d_in[1];
  const int*   batch     = (const int*)d_in[2];
  const float* edge_attr = (const float*)d_in[3];
  const float* atom_emb  = (const float*)d_in[4];
  const float* edge_w    = (const float*)d_in[5];
  const float* edge_b    = (const float*)d_in[6];
  const float* pre_w1    = (const float*)d_in[7];
  const float* pre_b1    = (const float*)d_in[8];
  const float* pre_w2    = (const float*)d_in[9];
  const float* pre_b2    = (const float*)d_in[10];
  const float* post_w1   = (const float*)d_in[11];
  const float* post_b1   = (const float*)d_in[12];
  const float* post_w2   = (const float*)d_in[13];
  const float* post_b2   = (const float*)d_in[14];
  const float* lin_w     = (const float*)d_in[15];
  const float* lin_b     = (const float*)d_in[16];
  const float* bn_g      = (const float*)d_in[17];
  const float* bn_b      = (const float*)d_in[18];
  const float* mlp_w1    = (const float*)d_in[19];
  const float* mlp_b1    = (const float*)d_in[20];
  const float* mlp_w2    = (const float*)d_in[21];
  const float* mlp_b2    = (const float*)d_in[22];
  const float* mlp_w3    = (const float*)d_in[23];
  const float* mlp_b3    = (const float*)d_in[24];
  float* out = (float*)d_out;

  // workspace carve-up (~116 MB; ws confirmed >= ~250 MB by round-5 c=1 behavior)
  char* ws = (char*)d_ws;
  size_t off = 0;
  auto alloc = [&](size_t bytes) -> void* {
    void* p = ws + off;
    off += (bytes + 15) & ~(size_t)15;
    return p;
  };
  float* h       = (float*)alloc((size_t)NN * DD * 4);           // 16 MB
  float* out2    = (float*)alloc((size_t)NN * DD * 4);           // 16 MB
  unsigned short* predD = (unsigned short*)alloc((size_t)NN * DD * 2); // 8 MB bf16
  unsigned short* predS = (unsigned short*)alloc((size_t)NN * DD * 2); // 8 MB bf16
  int*   csr_src = (int*)alloc((size_t)EE * 4);                  // 3.2 MB
  int*   csr_eid = (int*)alloc((size_t)EE * 4);                  // 3.2 MB
  int*   csr_dst = (int*)alloc((size_t)EE * 4);                  // 3.2 MB
  unsigned int* ea16 = (unsigned int*)alloc((size_t)EE * 8 * 4); // 25.6 MB f16 CSR-ordered ea
  int*   row_ptr = (int*)alloc((size_t)(NN + 1) * 4);
  int*   cnt     = (int*)alloc((size_t)NN * 4);
  int*   cursor  = (int*)alloc((size_t)NN * 4);
  float* inv_deg = (float*)alloc((size_t)NN * 4);
  float* s1a     = (float*)alloc((size_t)NN * 4);
  float* s2a     = (float*)alloc((size_t)NN * 4);
  float* colsum  = (float*)alloc(2 * DD * 4);
  float* bnsc    = (float*)alloc(2 * DD * 4);
  float* gbuf    = (float*)alloc((size_t)GG * DD * 4);
  unsigned int* wcpk  = (unsigned int*)alloc((size_t)TT * FF * 8 * 4);
  unsigned int* w2pk  = (unsigned int*)alloc((size_t)TT * FF * 10 * 4);
  unsigned int* q1pk  = (unsigned int*)alloc((size_t)TT * 120 * FF * 4);
  unsigned int* q2pk  = (unsigned int*)alloc((size_t)TT * 10 * FF * 4);
  float* biasc   = (float*)alloc((size_t)TT * FF * 4);
  int*   bsum    = (int*)alloc((size_t)SCAN_B * 4);
  int*   boff    = (int*)alloc((size_t)SCAN_B * 4);
  int*   gcnt    = (int*)alloc((size_t)GG * 4);
  int*   gstart  = (int*)alloc((size_t)(GG + 1) * 4);
  unsigned short* aggbuf = (unsigned short*)alloc((size_t)NN * 4 * 80 * 2); // 32 MB bf16
  float* outl = (float*)aggbuf; // alias: aggbuf dead after k_post2; outl dead before next k_preagg
  (void)in_sizes; (void)n_in; (void)out_size; (void)ws_size;

  hipMemsetAsync(cnt, 0, (size_t)NN * 4, stream);
  k_h<<<(NN * DD + 255) / 256, 256, 0, stream>>>(x, atom_emb, h);
  k_deg<<<(EE + 255) / 256, 256, 0, stream>>>(ei, cnt);
  k_scan_sum<<<SCAN_B, 1024, 0, stream>>>(cnt, bsum);
  k_scan_top<<<1, 64, 0, stream>>>(bsum, boff, row_ptr);
  k_scan_apply<<<SCAN_B, 1024, 0, stream>>>(cnt, boff, row_ptr, cursor);
  k_csrfill<<<(EE + 255) / 256, 256, 0, stream>>>(ei, cursor, csr_src, csr_eid, csr_dst);
  k_eagather<<<(EE + 255) / 256, 256, 0, stream>>>(csr_eid, edge_attr, ea16);
  k_nodeparams<<<(NN + 255) / 256, 256, 0, stream>>>(cnt, inv_deg, s1a, s2a);

  int tilesA = (NN + TILE_N - 1) / TILE_N;   // 1563
  int tilesP = (NN + 255) / 256;             // 196
  for (int l = 0; l < LL; ++l) {
    k_wcomb<<<TT, 64, 0, stream>>>(edge_w, edge_b, pre_w1, pre_b1, pre_w2, wcpk, w2pk, biasc, l);
    k_postpk<<<TT, 64, 0, stream>>>(post_w1, post_w2, q1pk, q2pk, l);
    k_prenode<<<(NN + 63) / 64, 256, 0, stream>>>(h, pre_w1, biasc, predD, predS, l);
    k_preagg<<<tilesA * TT, 256, 0, stream>>>(predD, predS, ea16, csr_src, csr_dst, row_ptr,
        inv_deg, wcpk, w2pk, pre_b2, aggbuf, l, tilesA);
    k_post2<<<tilesP * TT, 256, 0, stream>>>(h, aggbuf, s1a, s2a,
        post_w1, post_b1, q1pk, q2pk, post_b2, out2, l, tilesP);
    hipMemsetAsync(colsum, 0, 2 * DD * 4, stream);
    k_lin<<<512, 320, 0, stream>>>(out2, lin_w, lin_b, outl, colsum, l);
    k_bnfinal<<<1, 128, 0, stream>>>(colsum, bn_g, bn_b, bnsc, l);
    k_bnapply<<<(NN * DD + 255) / 256, 256, 0, stream>>>(outl, bnsc, h);
  }

  hipMemsetAsync(gcnt, 0, (size_t)GG * 4, stream);
  k_gcnt<<<(NN + 255) / 256, 256, 0, stream>>>(batch, gcnt);
  k_gstart<<<1, 64, 0, stream>>>(gcnt, gstart);
  k_gmean<<<GG, 320, 0, stream>>>(h, gstart, gcnt, gbuf);
  k_mlp<<<GG, 64, 0, stream>>>(gbuf, mlp_w1, mlp_b1, mlp_w2, mlp_b2, mlp_w3, mlp_b3, out);
}